// Round 14
// baseline (3522.506 us; speedup 1.0000x reference)
//
#include <hip/hip_runtime.h>
#include <hip/hip_fp16.h>
#include <cstdint>

// Problem constants (B=4, S=4096, D=1024)
#define NRALL 16384
#define DM    1024
#define DI    2048
#define SEQL  4096

typedef _Float16 f16;
typedef _Float16 f16x8 __attribute__((ext_vector_type(8)));
typedef _Float16 f16x4 __attribute__((ext_vector_type(4)));
typedef _Float16 f16x2 __attribute__((ext_vector_type(2)));
typedef float    f32x4 __attribute__((ext_vector_type(4)));

__device__ __forceinline__ float phi_f(float t)  { return t > 0.0f ? t + 1.0f : __expf(t); }
__device__ __forceinline__ float silu_f(float t) { return t / (1.0f + __expf(-t)); }

#define GLDS16(g, l)                                                            \
    __builtin_amdgcn_global_load_lds(                                           \
        (const __attribute__((address_space(1))) void*)(g),                     \
        (__attribute__((address_space(3))) void*)(l), 16, 0, 0)

// ---------------- 1. merged prep: rmsnorm rows + weight format ------------------
__device__ __forceinline__ void wfmt_one(const float* __restrict__ W, char* __restrict__ fmt,
                                         int n, int kt, int Nw, int Ntot, int noff)
{
    const int ng = noff + n;
#pragma unroll
    for (int kh = 0; kh < 2; ++kh) {
        char* o = fmt + ((size_t)(kt * 2 + kh) * Ntot + ng) * 64;
#pragma unroll
        for (int c2 = 0; c2 < 4; ++c2) {
            f16x8 p;
#pragma unroll
            for (int j = 0; j < 8; ++j)
                p[j] = (f16)W[(size_t)(kt * 64 + kh * 32 + c2 * 8 + j) * Nw + n];
            *(f16x8*)(o + ((c2 ^ ((ng >> 1) & 3)) << 4)) = p;
        }
    }
}

__global__ __launch_bounds__(256) void prep_k(const float* __restrict__ x,
                                              const float* __restrict__ nw,
                                              f16* __restrict__ xn,
                                              const float* __restrict__ w_up,
                                              const float* __restrict__ w_gate,
                                              const float* __restrict__ w_down,
                                              const float* __restrict__ wq,
                                              const float* __restrict__ wk,
                                              const float* __restrict__ wv,
                                              const float* __restrict__ wo,
                                              char* __restrict__ fmtUG,
                                              char* __restrict__ fmtD,
                                              char* __restrict__ fmtQKV,
                                              char* __restrict__ fmtO)
{
    const int t = threadIdx.x;
    if (blockIdx.x < NRALL) {
        const int r = blockIdx.x;
        const float4 v = *(const float4*)(x + (size_t)r * DM + t * 4);
        float s = v.x * v.x + v.y * v.y + v.z * v.z + v.w * v.w;
#pragma unroll
        for (int m = 1; m < 64; m <<= 1) s += __shfl_xor(s, m);
        __shared__ float ws4[4];
        if ((t & 63) == 0) ws4[t >> 6] = s;
        __syncthreads();
        const float tot = ws4[0] + ws4[1] + ws4[2] + ws4[3];
        const float sc = rsqrtf(tot * (1.0f / DM) + 1e-5f);
        const float4 w = *(const float4*)(nw + t * 4);
        f16x4 o;
        o[0] = (f16)(v.x * sc * w.x); o[1] = (f16)(v.y * sc * w.y);
        o[2] = (f16)(v.z * sc * w.z); o[3] = (f16)(v.w * sc * w.w);
        *(f16x4*)(xn + (size_t)r * DM + t * 4) = o;
        return;
    }
    int id = blockIdx.x - NRALL;
    if (id < 128) { wfmt_one(w_up,   fmtUG,  (id % 8) * 256 + t, id / 8, DI, 4096, 0);    return; }
    id -= 128;
    if (id < 128) { wfmt_one(w_gate, fmtUG,  (id % 8) * 256 + t, id / 8, DI, 4096, 2048); return; }
    id -= 128;
    if (id < 128) { wfmt_one(w_down, fmtD,   (id % 4) * 256 + t, id / 4, DM, 1024, 0);    return; }
    id -= 128;
    if (id < 64)  { wfmt_one(wq,     fmtQKV, (id % 4) * 256 + t, id / 4, DM, 3072, 0);    return; }
    id -= 64;
    if (id < 64)  { wfmt_one(wk,     fmtQKV, (id % 4) * 256 + t, id / 4, DM, 3072, 1024); return; }
    id -= 64;
    if (id < 64)  { wfmt_one(wv,     fmtQKV, (id % 4) * 256 + t, id / 4, DM, 3072, 2048); return; }
    id -= 64;
    wfmt_one(wo, fmtO, (id % 4) * 256 + t, id / 4, DM, 1024, 0);
}

// ---------------- 2. 256x256 MFMA GEMM, BK=32, 64KB LDS, 2 blocks/CU ------------
// 512 thr = 8 waves (2m x 4n), per-wave 128x64, acc 128 VGPR.
// LDS 64KB: A 2buf x 16KB (256 rows x 32k) + B 2buf x 16KB (256 cols x 32k).
// One phase per K32-tile: stage(p^1, t+1) -> 12 ds_read(p) -> lgkm0 -> vmcnt(0)
// -> barrier -> 32 MFMA. Correctness:
//  RAW: every wave vmcnt(0)-drains its own stage glds BEFORE the barrier; reads
//       of those slots issue after the barrier (all waves' DMA certified).
//  WAR: reader drains its reads (lgkm0) pre-barrier(t); overwriting stage of the
//       same slots issues post-barrier(t) in tile t+1.
// The pre-barrier drain stall is covered by the co-resident second block (the
// point of halving LDS): 2 independent blocks/CU overlap barrier stalls w/ MFMA.
template <int EPI>
__global__ __launch_bounds__(512, 4) void mg256_k(const f16* __restrict__ A, int lda,
                                                  const char* __restrict__ fmt,
                                                  void* __restrict__ Cv,
                                                  int N, int K, int gx,
                                                  const float* __restrict__ addx)
{
    __shared__ __align__(16) char ldsb[65536];

    const int t = threadIdx.x;
    int wid = blockIdx.x;
    { const int cpx = gridDim.x >> 3; wid = (wid & 7) * cpx + (wid >> 3); }  // XCD swizzle
    const int bx = wid % gx, by = wid / gx;
    const int bm = by * 256, bn = bx * 256;
    const int lane = t & 63, wv = t >> 6;
    const int wm = wv >> 2, wn = wv & 3;        // 2m x 4n
    const int kb = lane >> 4, lr16 = lane & 15;
    const int NT = K >> 5;                      // K32 tiles

    f32x4 acc[8][4];
#pragma unroll
    for (int i = 0; i < 8; ++i)
#pragma unroll
        for (int j = 0; j < 4; ++j) acc[i][j] = (f32x4)0.0f;

    // staging: 1024 chunks of 16B per operand buf; thread covers ii = t, t+512
    const int r0i = t >> 2, s0i = t & 3;
    const int r1i = (t + 512) >> 2, s1i = t & 3;
    const f16* Ab0 = A + (size_t)(bm + r0i) * lda + (s0i ^ ((r0i >> 1) & 3)) * 8;
    const f16* Ab1 = A + (size_t)(bm + r1i) * lda + (s1i ^ ((r1i >> 1) & 3)) * 8;
    const char* Bb = fmt + (size_t)bn * 64 + (size_t)t * 16;
    const size_t BKstep = (size_t)N * 64;

    auto STAGE_A = [&](int p, int kt) {
        GLDS16(Ab0 + kt * 32, ldsb + p * 16384 + t * 16);
        GLDS16(Ab1 + kt * 32, ldsb + p * 16384 + 8192 + t * 16);
    };
    auto STAGE_B = [&](int p, int kt) {
        GLDS16(Bb + (size_t)kt * BKstep, ldsb + 32768 + p * 16384 + t * 16);
        GLDS16(Bb + (size_t)kt * BKstep + 8192, ldsb + 32768 + p * 16384 + 8192 + t * 16);
    };

    f16x8 af[8], bf[4];

    // prologue: stage tile 0 into buf0, certify, barrier
    STAGE_A(0, 0); STAGE_B(0, 0);
    asm volatile("s_waitcnt vmcnt(0)" ::: "memory");
    __builtin_amdgcn_s_barrier();
    __builtin_amdgcn_sched_barrier(0);

    for (int tt = 0; tt < NT; ++tt) {
        const int p = tt & 1;
        const int tn = tt + 1 < NT ? tt + 1 : NT - 1;
        // stage next tile first (maximizes glds age at the vmcnt(0) drain)
        STAGE_A(p ^ 1, tn); STAGE_B(p ^ 1, tn);
        // fragment reads for this tile
#pragma unroll
        for (int q = 0; q < 8; ++q) {
            const int row = wm * 128 + q * 16 + lr16;
            af[q] = *(const f16x8*)(ldsb + p * 16384 + row * 64 + ((kb ^ ((row >> 1) & 3)) << 4));
        }
#pragma unroll
        for (int j = 0; j < 4; ++j) {
            const int n = wn * 64 + j * 16 + lr16;
            bf[j] = *(const f16x8*)(ldsb + 32768 + p * 16384 + n * 64 + ((kb ^ ((n >> 1) & 3)) << 4));
        }
        asm volatile("s_waitcnt lgkmcnt(0)" ::: "memory");   // own reads drained (WAR)
        asm volatile("s_waitcnt vmcnt(0)" ::: "memory");     // own stages landed (RAW)
        __builtin_amdgcn_sched_barrier(0);
        __builtin_amdgcn_s_barrier();
        __builtin_amdgcn_sched_barrier(0);
        __builtin_amdgcn_s_setprio(1);
#pragma unroll
        for (int q = 0; q < 8; ++q) {
            acc[q][0] = __builtin_amdgcn_mfma_f32_16x16x32_f16(af[q], bf[0], acc[q][0], 0, 0, 0);
            acc[q][1] = __builtin_amdgcn_mfma_f32_16x16x32_f16(af[q], bf[1], acc[q][1], 0, 0, 0);
            acc[q][2] = __builtin_amdgcn_mfma_f32_16x16x32_f16(af[q], bf[2], acc[q][2], 0, 0, 0);
            acc[q][3] = __builtin_amdgcn_mfma_f32_16x16x32_f16(af[q], bf[3], acc[q][3], 0, 0, 0);
        }
        __builtin_amdgcn_s_setprio(0);
        __builtin_amdgcn_sched_barrier(0);
    }
    asm volatile("s_waitcnt vmcnt(0)" ::: "memory");  // drain trailing DMA

    // ---- epilogue: C frag col=lane&15, row=(lane>>4)*4+r
#pragma unroll
    for (int fm = 0; fm < 8; ++fm) {
        const int row0 = bm + wm * 128 + fm * 16 + kb * 4;
#pragma unroll
        for (int fn = 0; fn < 4; ++fn) {
            const int col = bn + wn * 64 + fn * 16 + lr16;
#pragma unroll
            for (int r = 0; r < 4; ++r) {
                float o = acc[fm][fn][r];
                if (EPI == 1) {
                    if (col < DM) o = phi_f(o) * 0.125f;
                    else if (col < 2 * DM) o = phi_f(o);
                }
                if (EPI == 2) {
                    ((float*)Cv)[(size_t)(row0 + r) * N + col] =
                        o + addx[(size_t)(row0 + r) * N + col];
                } else {
                    ((f16*)Cv)[(size_t)(row0 + r) * N + col] = (f16)o;
                }
            }
        }
    }
}

// ---------------- 3. causal dwconv + silu + gate, rolling window ----------------
__global__ __launch_bounds__(256) void conv_gate_k(f16* __restrict__ upg,
                                                   const float* __restrict__ cw,
                                                   const float* __restrict__ cb)
{
    const int r0 = blockIdx.x * 16;
    const int c = threadIdx.x * 8;
    float bias[8];
    {
        const float4 b0 = *(const float4*)(cb + c);
        const float4 b1 = *(const float4*)(cb + c + 4);
        bias[0] = b0.x; bias[1] = b0.y; bias[2] = b0.z; bias[3] = b0.w;
        bias[4] = b1.x; bias[5] = b1.y; bias[6] = b1.z; bias[7] = b1.w;
    }
    float tap[8][4];
#pragma unroll
    for (int j = 0; j < 8; ++j)
        *(float4*)tap[j] = *(const float4*)(cw + (size_t)(c + j) * 4);

    const bool lead = (r0 & (SEQL - 1)) == 0;
    f16x8 w0, w1, w2;
    if (lead) {
        w0 = (f16x8)(f16)0; w1 = (f16x8)(f16)0; w2 = (f16x8)(f16)0;
    } else {
        w0 = *(const f16x8*)(upg + (size_t)(r0 - 3) * 4096 + c);
        w1 = *(const f16x8*)(upg + (size_t)(r0 - 2) * 4096 + c);
        w2 = *(const f16x8*)(upg + (size_t)(r0 - 1) * 4096 + c);
    }
#pragma unroll 4
    for (int i = 0; i < 16; ++i) {
        const size_t row = (size_t)(r0 + i);
        const f16x8 w3 = *(const f16x8*)(upg + row * 4096 + c);
        const f16x8 g  = *(const f16x8*)(upg + row * 4096 + 2048 + c);
        f16x8 o;
#pragma unroll
        for (int j = 0; j < 8; ++j) {
            float a = bias[j];
            a = fmaf((float)w0[j], tap[j][0], a);
            a = fmaf((float)w1[j], tap[j][1], a);
            a = fmaf((float)w2[j], tap[j][2], a);
            a = fmaf((float)w3[j], tap[j][3], a);
            o[j] = (f16)(silu_f((float)g[j]) * silu_f(a));
        }
        *(f16x8*)(upg + row * 4096 + 2048 + c) = o;
        w0 = w1; w1 = w2; w2 = w3;
    }
}

// ---------------- 4a. per-chunk outer products: GT[b][h][ch][e][d] = (K^T V)^T --
__global__ __launch_bounds__(256) void gscan_g_k(const f16* __restrict__ qkv,
                                                 f16* __restrict__ GT)
{
    __shared__ float Ks[4096];
    __shared__ float Vs[4096];
    const int t = threadIdx.x, ch = blockIdx.x, h = blockIdx.y, b = blockIdx.z;
    const int r = t >> 2, c16 = (t & 3) * 16;
    const f16* kp = qkv + ((size_t)b * SEQL + ch * 64 + r) * 3072 + DM + h * 64 + c16;
#pragma unroll
    for (int i = 0; i < 2; ++i) {
        const f16x8 kv = *(const f16x8*)(kp + 8 * i);
        const f16x8 vv = *(const f16x8*)(kp + DM + 8 * i);
#pragma unroll
        for (int j = 0; j < 8; ++j) {
            Ks[r * 64 + c16 + 8 * i + j] = (float)kv[j];
            Vs[r * 64 + c16 + 8 * i + j] = (float)vv[j];
        }
    }
    __syncthreads();
    const int e4 = (t >> 4) * 4, d4 = (t & 15) * 4;
    float4 ag[4] = {};
#pragma unroll 4
    for (int c = 0; c < 64; ++c) {
        float va[4];
        *(float4*)va = *(const float4*)(Vs + c * 64 + e4);
        const float4 ka = *(const float4*)(Ks + c * 64 + d4);
        ag[0].x = fmaf(va[0], ka.x, ag[0].x); ag[0].y = fmaf(va[0], ka.y, ag[0].y);
        ag[0].z = fmaf(va[0], ka.z, ag[0].z); ag[0].w = fmaf(va[0], ka.w, ag[0].w);
        ag[1].x = fmaf(va[1], ka.x, ag[1].x); ag[1].y = fmaf(va[1], ka.y, ag[1].y);
        ag[1].z = fmaf(va[1], ka.z, ag[1].z); ag[1].w = fmaf(va[1], ka.w, ag[1].w);
        ag[2].x = fmaf(va[2], ka.x, ag[2].x); ag[2].y = fmaf(va[2], ka.y, ag[2].y);
        ag[2].z = fmaf(va[2], ka.z, ag[2].z); ag[2].w = fmaf(va[2], ka.w, ag[2].w);
        ag[3].x = fmaf(va[3], ka.x, ag[3].x); ag[3].y = fmaf(va[3], ka.y, ag[3].y);
        ag[3].z = fmaf(va[3], ka.z, ag[3].z); ag[3].w = fmaf(va[3], ka.w, ag[3].w);
    }
    f16* go = GT + (((size_t)b * 16 + h) * 64 + ch) * 4096 + e4 * 64 + d4;
#pragma unroll
    for (int i = 0; i < 4; ++i) {
        f16x4 o;
        o[0] = (f16)ag[i].x; o[1] = (f16)ag[i].y;
        o[2] = (f16)ag[i].z; o[3] = (f16)ag[i].w;
        *(f16x4*)(go + i * 64) = o;
    }
}

// ---------------- 4b. in-place exclusive prefix over chunks (f16x2, fp32 carry) -
__global__ __launch_bounds__(256) void gprefix_k(f16* __restrict__ G)
{
    const int bh = blockIdx.x >> 3, sl = blockIdx.x & 7;
    f16x2* p = (f16x2*)(G + (size_t)bh * 64 * 4096) + sl * 256 + threadIdx.x;
    float r0 = 0.0f, r1 = 0.0f;
#pragma unroll 4
    for (int ch = 0; ch < 64; ++ch) {
        const f16x2 g = *p;
        f16x2 o; o[0] = (f16)r0; o[1] = (f16)r1;
        *p = o;
        r0 += (float)g[0]; r1 += (float)g[1];
        p += 2048;
    }
}

// ---------------- 4c. per-chunk read via MFMA: y = q*M_excl + tril(q k^T) v -----
__global__ __launch_bounds__(256) void gscan_y_k(const f16* __restrict__ qkv,
                                                 const f16* __restrict__ GT,
                                                 f16* __restrict__ y)
{
    __shared__ __align__(16) char lds[40960];
    f16* Qs = (f16*)lds;
    f16* Ks = (f16*)(lds + 8192);
    f16* Ms = (f16*)(lds + 16384);
    f16* Vt = (f16*)(lds + 24576);
    f16* Ss = (f16*)(lds + 32768);

    const int t = threadIdx.x, ch = blockIdx.x, h = blockIdx.y, b = blockIdx.z;
    const int lane = t & 63, w = t >> 6;
    const int kb = lane >> 4, lr16 = lane & 15;

    const int r = t >> 2;
    const int c0 = (t & 3) * 2;
    const int rkey = (r >> 1) & 3;
    const f16* qp = qkv + ((size_t)b * SEQL + ch * 64 + r) * 3072 + h * 64;
    const f16* mp = GT + (((size_t)b * 16 + h) * 64 + ch) * 4096 + r * 64;
#pragma unroll
    for (int cc = 0; cc < 2; ++cc) {
        const int c = c0 + cc;
        const int sw = c ^ rkey;
        const f16x8 qv = *(const f16x8*)(qp + c * 8);
        const f16x8 kv = *(const f16x8*)(qp + DM + c * 8);
        const f16x8 vv = *(const f16x8*)(qp + 2 * DM + c * 8);
        const f16x8 mv = *(const f16x8*)(mp + c * 8);
        *(f16x8*)(Qs + r * 64 + sw * 8) = qv;
        *(f16x8*)(Ks + r * 64 + sw * 8) = kv;
        *(f16x8*)(Ms + r * 64 + sw * 8) = mv;
#pragma unroll
        for (int jj = 0; jj < 8; ++jj) {
            const int j = c * 8 + jj;
            Vt[j * 64 + ((((r >> 3) ^ ((j >> 1) & 3)) << 3) + (r & 7))] = vv[jj];
        }
    }
    __syncthreads();

    f16x8 af[2];
    {
        const int row = w * 16 + lr16;
        const int sz = (row >> 1) & 3;
        af[0] = *(const f16x8*)(Qs + row * 64 + (kb ^ sz) * 8);
        af[1] = *(const f16x8*)(Qs + row * 64 + (4 + (kb ^ sz)) * 8);
    }
    f32x4 accs[4];
#pragma unroll
    for (int te = 0; te < 4; ++te) accs[te] = (f32x4)0.0f;
#pragma unroll
    for (int te = 0; te < 4; ++te) {
        const int er = te * 16 + lr16;
        const int es = (er >> 1) & 3;
        const f16x8 b0 = *(const f16x8*)(Ks + er * 64 + (kb ^ es) * 8);
        const f16x8 b1 = *(const f16x8*)(Ks + er * 64 + (4 + (kb ^ es)) * 8);
        accs[te] = __builtin_amdgcn_mfma_f32_16x16x32_f16(af[0], b0, accs[te], 0, 0, 0);
        accs[te] = __builtin_amdgcn_mfma_f32_16x16x32_f16(af[1], b1, accs[te], 0, 0, 0);
    }
#pragma unroll
    for (int te = 0; te < 4; ++te)
#pragma unroll
        for (int rr = 0; rr < 4; ++rr) {
            const int rc = w * 16 + kb * 4 + rr;
            const int ce = te * 16 + lr16;
            const float v = (ce <= rc) ? accs[te][rr] : 0.0f;
            Ss[rc * 64 + ((((ce >> 3) ^ ((rc >> 1) & 3)) << 3) + (ce & 7))] = (f16)v;
        }
    __syncthreads();

    f16x8 as2[2];
    {
        const int row = w * 16 + lr16;
        const int sz = (row >> 1) & 3;
        as2[0] = *(const f16x8*)(Ss + row * 64 + (kb ^ sz) * 8);
        as2[1] = *(const f16x8*)(Ss + row * 64 + (4 + (kb ^ sz)) * 8);
    }
    f32x4 accy[4];
#pragma unroll
    for (int tj = 0; tj < 4; ++tj) accy[tj] = (f32x4)0.0f;
#pragma unroll
    for (int tj = 0; tj < 4; ++tj) {
        const int jr = tj * 16 + lr16;
        const int js = (jr >> 1) & 3;
        const f16x8 m0 = *(const f16x8*)(Ms + jr * 64 + (kb ^ js) * 8);
        const f16x8 m1 = *(const f16x8*)(Ms + jr * 64 + (4 + (kb ^ js)) * 8);
        const f16x8 v0 = *(const f16x8*)(Vt + jr * 64 + (kb ^ js) * 8);
        const f16x8 v1 = *(const f16x8*)(Vt + jr * 64 + (4 + (kb ^ js)) * 8);
        accy[tj] = __builtin_amdgcn_mfma_f32_16x16x32_f16(af[0],  m0, accy[tj], 0, 0, 0);
        accy[tj] = __builtin_amdgcn_mfma_f32_16x16x32_f16(af[1],  m1, accy[tj], 0, 0, 0);
        accy[tj] = __builtin_amdgcn_mfma_f32_16x16x32_f16(as2[0], v0, accy[tj], 0, 0, 0);
        accy[tj] = __builtin_amdgcn_mfma_f32_16x16x32_f16(as2[1], v1, accy[tj], 0, 0, 0);
    }
    f16* yo = y + ((size_t)b * SEQL + ch * 64) * DM + h * 64;
#pragma unroll
    for (int tj = 0; tj < 4; ++tj)
#pragma unroll
        for (int rr = 0; rr < 4; ++rr) {
            const int rc = w * 16 + kb * 4 + rr;
            yo[(size_t)rc * DM + tj * 16 + lr16] = (f16)accy[tj][rr];
        }
}

// ---------------- launch --------------------------------------------------------
extern "C" void kernel_launch(void* const* d_in, const int* in_sizes, int n_in,
                              void* d_out, int out_size, void* d_ws, size_t ws_size,
                              hipStream_t stream)
{
    const float* x      = (const float*)d_in[0];
    const float* norm_w = (const float*)d_in[1];
    const float* w_up   = (const float*)d_in[2];
    const float* w_gate = (const float*)d_in[3];
    const float* w_down = (const float*)d_in[4];
    const float* conv_w = (const float*)d_in[5];
    const float* conv_b = (const float*)d_in[6];
    const float* wq     = (const float*)d_in[7];
    const float* wk     = (const float*)d_in[8];
    const float* wv     = (const float*)d_in[9];
    const float* wo     = (const float*)d_in[10];
    float* out = (float*)d_out;

    const size_t BIG_NEED = 247463936ull;
    const bool big = ws_size >= BIG_NEED;

    if (big) {
        char* p = (char*)d_ws;
        f16* upg = (f16*)p;               p += (size_t)NRALL * 4096 * 2;
        f16* hb  = (f16*)p;               p += (size_t)NRALL * DM * 2;
        char* fmtD   = p;                 p += (size_t)64 * 1024 * 64;
        char* fmtQKV = p;                 p += (size_t)32 * 3072 * 64;
        char* fmtO   = p;                 p += (size_t)32 * 1024 * 64;
        f16* xn = (f16*)p;                p += (size_t)NRALL * DM * 2;
        char* fmtUG  = p;
        f16* G = (f16*)xn;                // overlays xn+fmtUG (dead after up/gate GEMM)
        f16* qkvb = upg;
        f16* yb   = hb;

        prep_k<<<NRALL + 640, 256, 0, stream>>>(x, norm_w, xn, w_up, w_gate, w_down,
                                                wq, wk, wv, wo, fmtUG, fmtD, fmtQKV, fmtO);

        mg256_k<0><<<16 * 64, 512, 0, stream>>>(xn, DM, fmtUG, upg, 4096, DM, 16, nullptr);
        conv_gate_k<<<NRALL / 16, 256, 0, stream>>>(upg, conv_w, conv_b);
        mg256_k<0><<<4 * 64, 512, 0, stream>>>(upg + 2048, 4096, fmtD, hb, 1024, DI, 4, nullptr);
        mg256_k<1><<<12 * 64, 512, 0, stream>>>(hb, DM, fmtQKV, qkvb, 3072, DM, 12, nullptr);

        gscan_g_k<<<dim3(64, 16, 4), 256, 0, stream>>>(qkvb, G);
        gprefix_k<<<512, 256, 0, stream>>>(G);
        gscan_y_k<<<dim3(64, 16, 4), 256, 0, stream>>>(qkvb, G, yb);

        mg256_k<2><<<4 * 64, 512, 0, stream>>>(yb, DM, fmtO, out, 1024, DM, 4, x);
    } else {
        // compact per-batch path
        char* p = (char*)d_ws;
        f16* xn = (f16*)p;                p += (size_t)NRALL * DM * 2;
        f16* upg = (f16*)p;               p += (size_t)SEQL * 4096 * 2;
        f16* hb  = (f16*)p;               p += (size_t)SEQL * DM * 2;
        f16* G = (f16*)p;                 p += (size_t)16 * 64 * 4096 * 2;
        char* fmtUG  = p;                 p += (size_t)32 * 4096 * 64;
        char* fmtD   = p;                 p += (size_t)64 * 1024 * 64;
        char* fmtQKV = p;                 p += (size_t)32 * 3072 * 64;
        char* fmtO   = p;
        f16* qkvb = upg;
        f16* yb   = hb;

        prep_k<<<NRALL + 640, 256, 0, stream>>>(x, norm_w, xn, w_up, w_gate, w_down,
                                                wq, wk, wv, wo, fmtUG, fmtD, fmtQKV, fmtO);

        for (int b = 0; b < 4; ++b) {
            const f16* xnb = xn + (size_t)b * SEQL * DM;
            mg256_k<0><<<16 * 16, 512, 0, stream>>>(xnb, DM, fmtUG, upg, 4096, DM, 16, nullptr);
            conv_gate_k<<<SEQL / 16, 256, 0, stream>>>(upg, conv_w, conv_b);
            mg256_k<0><<<4 * 16, 512, 0, stream>>>(upg + 2048, 4096, fmtD, hb, 1024, DI, 4, nullptr);
            mg256_k<1><<<12 * 16, 512, 0, stream>>>(hb, DM, fmtQKV, qkvb, 3072, DM, 12, nullptr);
            gscan_g_k<<<dim3(64, 16, 1), 256, 0, stream>>>(qkvb, G);
            gprefix_k<<<128, 256, 0, stream>>>(G);
            gscan_y_k<<<dim3(64, 16, 1), 256, 0, stream>>>(qkvb, G, yb);
            mg256_k<2><<<4 * 16, 512, 0, stream>>>(yb, DM, fmtO,
                                                   out + (size_t)b * SEQL * DM, 1024, DM, 4,
                                                   x + (size_t)b * SEQL * DM);
        }
    }
}

// Round 15
// 532.413 us; speedup vs baseline: 6.6161x; 6.6161x over previous
//
#include <hip/hip_runtime.h>
#include <hip/hip_fp16.h>
#include <cstdint>

// Problem constants (B=4, S=4096, D=1024)
#define NRALL 16384
#define DM    1024
#define DI    2048
#define SEQL  4096

typedef _Float16 f16;
typedef _Float16 f16x8 __attribute__((ext_vector_type(8)));
typedef _Float16 f16x4 __attribute__((ext_vector_type(4)));
typedef _Float16 f16x2 __attribute__((ext_vector_type(2)));
typedef float    f32x4 __attribute__((ext_vector_type(4)));

__device__ __forceinline__ float phi_f(float t)  { return t > 0.0f ? t + 1.0f : __expf(t); }
__device__ __forceinline__ float silu_f(float t) { return t / (1.0f + __expf(-t)); }

#define GLDS16(g, l)                                                            \
    __builtin_amdgcn_global_load_lds(                                           \
        (const __attribute__((address_space(1))) void*)(g),                     \
        (__attribute__((address_space(3))) void*)(l), 16, 0, 0)

// ---------------- 1. merged prep: rmsnorm rows + weight format ------------------
__device__ __forceinline__ void wfmt_one(const float* __restrict__ W, char* __restrict__ fmt,
                                         int n, int kt, int Nw, int Ntot, int noff)
{
    const int ng = noff + n;
#pragma unroll
    for (int kh = 0; kh < 2; ++kh) {
        char* o = fmt + ((size_t)(kt * 2 + kh) * Ntot + ng) * 64;
#pragma unroll
        for (int c2 = 0; c2 < 4; ++c2) {
            f16x8 p;
#pragma unroll
            for (int j = 0; j < 8; ++j)
                p[j] = (f16)W[(size_t)(kt * 64 + kh * 32 + c2 * 8 + j) * Nw + n];
            *(f16x8*)(o + ((c2 ^ ((ng >> 1) & 3)) << 4)) = p;
        }
    }
}

__global__ __launch_bounds__(256) void prep_k(const float* __restrict__ x,
                                              const float* __restrict__ nw,
                                              f16* __restrict__ xn,
                                              const float* __restrict__ w_up,
                                              const float* __restrict__ w_gate,
                                              const float* __restrict__ w_down,
                                              const float* __restrict__ wq,
                                              const float* __restrict__ wk,
                                              const float* __restrict__ wv,
                                              const float* __restrict__ wo,
                                              char* __restrict__ fmtUG,
                                              char* __restrict__ fmtD,
                                              char* __restrict__ fmtQKV,
                                              char* __restrict__ fmtO)
{
    const int t = threadIdx.x;
    if (blockIdx.x < NRALL) {
        const int r = blockIdx.x;
        const float4 v = *(const float4*)(x + (size_t)r * DM + t * 4);
        float s = v.x * v.x + v.y * v.y + v.z * v.z + v.w * v.w;
#pragma unroll
        for (int m = 1; m < 64; m <<= 1) s += __shfl_xor(s, m);
        __shared__ float ws4[4];
        if ((t & 63) == 0) ws4[t >> 6] = s;
        __syncthreads();
        const float tot = ws4[0] + ws4[1] + ws4[2] + ws4[3];
        const float sc = rsqrtf(tot * (1.0f / DM) + 1e-5f);
        const float4 w = *(const float4*)(nw + t * 4);
        f16x4 o;
        o[0] = (f16)(v.x * sc * w.x); o[1] = (f16)(v.y * sc * w.y);
        o[2] = (f16)(v.z * sc * w.z); o[3] = (f16)(v.w * sc * w.w);
        *(f16x4*)(xn + (size_t)r * DM + t * 4) = o;
        return;
    }
    int id = blockIdx.x - NRALL;
    if (id < 128) { wfmt_one(w_up,   fmtUG,  (id % 8) * 256 + t, id / 8, DI, 4096, 0);    return; }
    id -= 128;
    if (id < 128) { wfmt_one(w_gate, fmtUG,  (id % 8) * 256 + t, id / 8, DI, 4096, 2048); return; }
    id -= 128;
    if (id < 128) { wfmt_one(w_down, fmtD,   (id % 4) * 256 + t, id / 4, DM, 1024, 0);    return; }
    id -= 128;
    if (id < 64)  { wfmt_one(wq,     fmtQKV, (id % 4) * 256 + t, id / 4, DM, 3072, 0);    return; }
    id -= 64;
    if (id < 64)  { wfmt_one(wk,     fmtQKV, (id % 4) * 256 + t, id / 4, DM, 3072, 1024); return; }
    id -= 64;
    if (id < 64)  { wfmt_one(wv,     fmtQKV, (id % 4) * 256 + t, id / 4, DM, 3072, 2048); return; }
    id -= 64;
    wfmt_one(wo, fmtO, (id % 4) * 256 + t, id / 4, DM, 1024, 0);
}

// ---------------- 2. 256x256 MFMA GEMM, 16 waves (4m x 4n), 8-phase -------------
// (round-13 proven version: 143 µs upgate, MfmaUtil 46%; parked)
#define PH(p, ks, mh, STAGE_STMT)                                                 \
    {                                                                             \
        if ((mh) == 0) {                                                          \
            _Pragma("unroll")                                                     \
            for (int q = 0; q < 2; ++q) {                                         \
                const int row = wm * 64 + q * 16 + lr16;                          \
                af[q] = *(const f16x8*)(ldsb + (p) * 32768 + (ks) * 16384         \
                        + row * 64 + ((kb ^ ((row >> 1) & 3)) << 4));             \
            }                                                                     \
            _Pragma("unroll")                                                     \
            for (int q = 0; q < 4; ++q) {                                         \
                const int n = wn * 64 + q * 16 + lr16;                            \
                bf[q] = *(const f16x8*)(ldsb + 65536 + (p) * 32768 + (ks) * 16384 \
                        + n * 64 + ((kb ^ ((n >> 1) & 3)) << 4));                 \
            }                                                                     \
        } else {                                                                  \
            _Pragma("unroll")                                                     \
            for (int q = 0; q < 2; ++q) {                                         \
                const int row = wm * 64 + (q + 2) * 16 + lr16;                    \
                af[2 + q] = *(const f16x8*)(ldsb + (p) * 32768 + (ks) * 16384     \
                            + row * 64 + ((kb ^ ((row >> 1) & 3)) << 4));         \
            }                                                                     \
        }                                                                         \
        STAGE_STMT;                                                               \
        asm volatile("s_waitcnt vmcnt(3)" ::: "memory");                          \
        __builtin_amdgcn_sched_barrier(0);                                        \
        __builtin_amdgcn_s_barrier();                                             \
        asm volatile("s_waitcnt lgkmcnt(0)" ::: "memory");                        \
        __builtin_amdgcn_sched_barrier(0);                                        \
        __builtin_amdgcn_s_setprio(1);                                            \
        _Pragma("unroll")                                                         \
        for (int q = 0; q < 2; ++q) {                                             \
            acc[(mh) * 2 + q][0] = __builtin_amdgcn_mfma_f32_16x16x32_f16(        \
                af[(mh) * 2 + q], bf[0], acc[(mh) * 2 + q][0], 0, 0, 0);          \
            acc[(mh) * 2 + q][1] = __builtin_amdgcn_mfma_f32_16x16x32_f16(        \
                af[(mh) * 2 + q], bf[1], acc[(mh) * 2 + q][1], 0, 0, 0);          \
            acc[(mh) * 2 + q][2] = __builtin_amdgcn_mfma_f32_16x16x32_f16(        \
                af[(mh) * 2 + q], bf[2], acc[(mh) * 2 + q][2], 0, 0, 0);          \
            acc[(mh) * 2 + q][3] = __builtin_amdgcn_mfma_f32_16x16x32_f16(        \
                af[(mh) * 2 + q], bf[3], acc[(mh) * 2 + q][3], 0, 0, 0);          \
        }                                                                         \
        __builtin_amdgcn_s_setprio(0);                                            \
        __builtin_amdgcn_sched_barrier(0);                                        \
    }

template <int EPI>
__global__ __launch_bounds__(1024) void mg256_k(const f16* __restrict__ A, int lda,
                                                const char* __restrict__ fmt,
                                                void* __restrict__ Cv,
                                                int N, int K, int gx,
                                                const float* __restrict__ addx)
{
    __shared__ __align__(16) char ldsb[131072];

    const int t = threadIdx.x;
    int wid = blockIdx.x;
    { const int cpx = gridDim.x >> 3; wid = (wid & 7) * cpx + (wid >> 3); }  // XCD swizzle
    const int bx = wid % gx, by = wid / gx;
    const int bm = by * 256, bn = bx * 256;
    const int lane = t & 63, wv = t >> 6;
    const int wm = wv >> 2, wn = wv & 3;
    const int kb = lane >> 4, lr16 = lane & 15;
    const int NT = K >> 6;

    f32x4 acc[4][4];
#pragma unroll
    for (int i = 0; i < 4; ++i)
#pragma unroll
        for (int j = 0; j < 4; ++j) acc[i][j] = (f32x4)0.0f;

    const int arow = t >> 2;
    const int ac2 = (t & 3) ^ ((arow >> 1) & 3);
    const f16* Abase = A + (size_t)(bm + arow) * lda + ac2 * 8;
    const char* Bbase = fmt + (size_t)bn * 64 + (size_t)t * 16;
    const size_t BKstep = (size_t)N * 64;
    char* ldsT = ldsb + t * 16;

    auto STAGE_A = [&](int p, int kh, int kt) {
        GLDS16(Abase + kt * 64 + kh * 32, ldsT + p * 32768 + kh * 16384);
    };
    auto STAGE_B = [&](int p, int kh, int kt) {
        GLDS16(Bbase + (size_t)(kt * 2 + kh) * BKstep, ldsT + 65536 + p * 32768 + kh * 16384);
    };

    f16x8 af[4], bf[4];

    const int T1 = NT > 1 ? 1 : 0;
    STAGE_B(0, 0, 0); STAGE_A(0, 0, 0);
    STAGE_B(0, 1, 0); STAGE_A(0, 1, 0);
    STAGE_B(1, 0, T1); STAGE_A(1, 0, T1);
    asm volatile("s_waitcnt vmcnt(4)" ::: "memory");
    __builtin_amdgcn_s_barrier();
    __builtin_amdgcn_sched_barrier(0);

    const int NI = NT >> 1;
    for (int i = 0; i < NI; ++i) {
        const int tA = 2 * i + 1 < NT ? 2 * i + 1 : NT - 1;
        const int tB = 2 * i + 2 < NT ? 2 * i + 2 : NT - 1;
        const int tC = 2 * i + 3 < NT ? 2 * i + 3 : NT - 1;
        PH(0, 0, 0, STAGE_B(1, 1, tA))
        PH(0, 0, 1, STAGE_A(1, 1, tA))
        PH(0, 1, 0, STAGE_B(0, 0, tB))
        PH(0, 1, 1, STAGE_A(0, 0, tB))
        PH(1, 0, 0, STAGE_B(0, 1, tB))
        PH(1, 0, 1, STAGE_A(0, 1, tB))
        PH(1, 1, 0, STAGE_B(1, 0, tC))
        PH(1, 1, 1, STAGE_A(1, 0, tC))
    }
    asm volatile("s_waitcnt vmcnt(0)" ::: "memory");

#pragma unroll
    for (int fm = 0; fm < 4; ++fm) {
        const int row0 = bm + wm * 64 + fm * 16 + kb * 4;
#pragma unroll
        for (int fn = 0; fn < 4; ++fn) {
            const int col = bn + wn * 64 + fn * 16 + lr16;
#pragma unroll
            for (int r = 0; r < 4; ++r) {
                float o = acc[fm][fn][r];
                if (EPI == 1) {
                    if (col < DM) o = phi_f(o) * 0.125f;
                    else if (col < 2 * DM) o = phi_f(o);
                }
                if (EPI == 2) {
                    ((float*)Cv)[(size_t)(row0 + r) * N + col] =
                        o + addx[(size_t)(row0 + r) * N + col];
                } else {
                    ((f16*)Cv)[(size_t)(row0 + r) * N + col] = (f16)o;
                }
            }
        }
    }
}

// ---------------- 3. causal dwconv + silu + gate, rolling window ----------------
__global__ __launch_bounds__(256) void conv_gate_k(f16* __restrict__ upg,
                                                   const float* __restrict__ cw,
                                                   const float* __restrict__ cb)
{
    const int r0 = blockIdx.x * 16;
    const int c = threadIdx.x * 8;
    float bias[8];
    {
        const float4 b0 = *(const float4*)(cb + c);
        const float4 b1 = *(const float4*)(cb + c + 4);
        bias[0] = b0.x; bias[1] = b0.y; bias[2] = b0.z; bias[3] = b0.w;
        bias[4] = b1.x; bias[5] = b1.y; bias[6] = b1.z; bias[7] = b1.w;
    }
    float tap[8][4];
#pragma unroll
    for (int j = 0; j < 8; ++j)
        *(float4*)tap[j] = *(const float4*)(cw + (size_t)(c + j) * 4);

    const bool lead = (r0 & (SEQL - 1)) == 0;
    f16x8 w0, w1, w2;
    if (lead) {
        w0 = (f16x8)(f16)0; w1 = (f16x8)(f16)0; w2 = (f16x8)(f16)0;
    } else {
        w0 = *(const f16x8*)(upg + (size_t)(r0 - 3) * 4096 + c);
        w1 = *(const f16x8*)(upg + (size_t)(r0 - 2) * 4096 + c);
        w2 = *(const f16x8*)(upg + (size_t)(r0 - 1) * 4096 + c);
    }
#pragma unroll 4
    for (int i = 0; i < 16; ++i) {
        const size_t row = (size_t)(r0 + i);
        const f16x8 w3 = *(const f16x8*)(upg + row * 4096 + c);
        const f16x8 g  = *(const f16x8*)(upg + row * 4096 + 2048 + c);
        f16x8 o;
#pragma unroll
        for (int j = 0; j < 8; ++j) {
            float a = bias[j];
            a = fmaf((float)w0[j], tap[j][0], a);
            a = fmaf((float)w1[j], tap[j][1], a);
            a = fmaf((float)w2[j], tap[j][2], a);
            a = fmaf((float)w3[j], tap[j][3], a);
            o[j] = (f16)(silu_f((float)g[j]) * silu_f(a));
        }
        *(f16x8*)(upg + row * 4096 + 2048 + c) = o;
        w0 = w1; w1 = w2; w2 = w3;
    }
}

// ---------------- 4a. per-chunk outer products: GT[b][h][ch][e][d] = (K^T V)^T --
__global__ __launch_bounds__(256) void gscan_g_k(const f16* __restrict__ qkv,
                                                 f16* __restrict__ GT)
{
    __shared__ float Ks[4096];
    __shared__ float Vs[4096];
    const int t = threadIdx.x, ch = blockIdx.x, h = blockIdx.y, b = blockIdx.z;
    const int r = t >> 2, c16 = (t & 3) * 16;
    const f16* kp = qkv + ((size_t)b * SEQL + ch * 64 + r) * 3072 + DM + h * 64 + c16;
#pragma unroll
    for (int i = 0; i < 2; ++i) {
        const f16x8 kv = *(const f16x8*)(kp + 8 * i);
        const f16x8 vv = *(const f16x8*)(kp + DM + 8 * i);
#pragma unroll
        for (int j = 0; j < 8; ++j) {
            Ks[r * 64 + c16 + 8 * i + j] = (float)kv[j];
            Vs[r * 64 + c16 + 8 * i + j] = (float)vv[j];
        }
    }
    __syncthreads();
    const int e4 = (t >> 4) * 4, d4 = (t & 15) * 4;
    float4 ag[4] = {};
#pragma unroll 4
    for (int c = 0; c < 64; ++c) {
        float va[4];
        *(float4*)va = *(const float4*)(Vs + c * 64 + e4);
        const float4 ka = *(const float4*)(Ks + c * 64 + d4);
        ag[0].x = fmaf(va[0], ka.x, ag[0].x); ag[0].y = fmaf(va[0], ka.y, ag[0].y);
        ag[0].z = fmaf(va[0], ka.z, ag[0].z); ag[0].w = fmaf(va[0], ka.w, ag[0].w);
        ag[1].x = fmaf(va[1], ka.x, ag[1].x); ag[1].y = fmaf(va[1], ka.y, ag[1].y);
        ag[1].z = fmaf(va[1], ka.z, ag[1].z); ag[1].w = fmaf(va[1], ka.w, ag[1].w);
        ag[2].x = fmaf(va[2], ka.x, ag[2].x); ag[2].y = fmaf(va[2], ka.y, ag[2].y);
        ag[2].z = fmaf(va[2], ka.z, ag[2].z); ag[2].w = fmaf(va[2], ka.w, ag[2].w);
        ag[3].x = fmaf(va[3], ka.x, ag[3].x); ag[3].y = fmaf(va[3], ka.y, ag[3].y);
        ag[3].z = fmaf(va[3], ka.z, ag[3].z); ag[3].w = fmaf(va[3], ka.w, ag[3].w);
    }
    f16* go = GT + (((size_t)b * 16 + h) * 64 + ch) * 4096 + e4 * 64 + d4;
#pragma unroll
    for (int i = 0; i < 4; ++i) {
        f16x4 o;
        o[0] = (f16)ag[i].x; o[1] = (f16)ag[i].y;
        o[2] = (f16)ag[i].z; o[3] = (f16)ag[i].w;
        *(f16x4*)(go + i * 64) = o;
    }
}

// ---------------- 4b. in-place exclusive prefix over chunks (f16x2, fp32 carry) -
__global__ __launch_bounds__(256) void gprefix_k(f16* __restrict__ G)
{
    const int bh = blockIdx.x >> 3, sl = blockIdx.x & 7;
    f16x2* p = (f16x2*)(G + (size_t)bh * 64 * 4096) + sl * 256 + threadIdx.x;
    float r0 = 0.0f, r1 = 0.0f;
#pragma unroll 4
    for (int ch = 0; ch < 64; ++ch) {
        const f16x2 g = *p;
        f16x2 o; o[0] = (f16)r0; o[1] = (f16)r1;
        *p = o;
        r0 += (float)g[0]; r1 += (float)g[1];
        p += 2048;
    }
}

// ---------------- 4c. per-chunk read via MFMA: y = q*M_excl + tril(q k^T) v -----
__global__ __launch_bounds__(256) void gscan_y_k(const f16* __restrict__ qkv,
                                                 const f16* __restrict__ GT,
                                                 f16* __restrict__ y)
{
    __shared__ __align__(16) char lds[40960];
    f16* Qs = (f16*)lds;
    f16* Ks = (f16*)(lds + 8192);
    f16* Ms = (f16*)(lds + 16384);
    f16* Vt = (f16*)(lds + 24576);
    f16* Ss = (f16*)(lds + 32768);

    const int t = threadIdx.x, ch = blockIdx.x, h = blockIdx.y, b = blockIdx.z;
    const int lane = t & 63, w = t >> 6;
    const int kb = lane >> 4, lr16 = lane & 15;

    const int r = t >> 2;
    const int c0 = (t & 3) * 2;
    const int rkey = (r >> 1) & 3;
    const f16* qp = qkv + ((size_t)b * SEQL + ch * 64 + r) * 3072 + h * 64;
    const f16* mp = GT + (((size_t)b * 16 + h) * 64 + ch) * 4096 + r * 64;
#pragma unroll
    for (int cc = 0; cc < 2; ++cc) {
        const int c = c0 + cc;
        const int sw = c ^ rkey;
        const f16x8 qv = *(const f16x8*)(qp + c * 8);
        const f16x8 kv = *(const f16x8*)(qp + DM + c * 8);
        const f16x8 vv = *(const f16x8*)(qp + 2 * DM + c * 8);
        const f16x8 mv = *(const f16x8*)(mp + c * 8);
        *(f16x8*)(Qs + r * 64 + sw * 8) = qv;
        *(f16x8*)(Ks + r * 64 + sw * 8) = kv;
        *(f16x8*)(Ms + r * 64 + sw * 8) = mv;
#pragma unroll
        for (int jj = 0; jj < 8; ++jj) {
            const int j = c * 8 + jj;
            Vt[j * 64 + ((((r >> 3) ^ ((j >> 1) & 3)) << 3) + (r & 7))] = vv[jj];
        }
    }
    __syncthreads();

    f16x8 af[2];
    {
        const int row = w * 16 + lr16;
        const int sz = (row >> 1) & 3;
        af[0] = *(const f16x8*)(Qs + row * 64 + (kb ^ sz) * 8);
        af[1] = *(const f16x8*)(Qs + row * 64 + (4 + (kb ^ sz)) * 8);
    }
    f32x4 accs[4];
#pragma unroll
    for (int te = 0; te < 4; ++te) accs[te] = (f32x4)0.0f;
#pragma unroll
    for (int te = 0; te < 4; ++te) {
        const int er = te * 16 + lr16;
        const int es = (er >> 1) & 3;
        const f16x8 b0 = *(const f16x8*)(Ks + er * 64 + (kb ^ es) * 8);
        const f16x8 b1 = *(const f16x8*)(Ks + er * 64 + (4 + (kb ^ es)) * 8);
        accs[te] = __builtin_amdgcn_mfma_f32_16x16x32_f16(af[0], b0, accs[te], 0, 0, 0);
        accs[te] = __builtin_amdgcn_mfma_f32_16x16x32_f16(af[1], b1, accs[te], 0, 0, 0);
    }
#pragma unroll
    for (int te = 0; te < 4; ++te)
#pragma unroll
        for (int rr = 0; rr < 4; ++rr) {
            const int rc = w * 16 + kb * 4 + rr;
            const int ce = te * 16 + lr16;
            const float v = (ce <= rc) ? accs[te][rr] : 0.0f;
            Ss[rc * 64 + ((((ce >> 3) ^ ((rc >> 1) & 3)) << 3) + (ce & 7))] = (f16)v;
        }
    __syncthreads();

    f16x8 as2[2];
    {
        const int row = w * 16 + lr16;
        const int sz = (row >> 1) & 3;
        as2[0] = *(const f16x8*)(Ss + row * 64 + (kb ^ sz) * 8);
        as2[1] = *(const f16x8*)(Ss + row * 64 + (4 + (kb ^ sz)) * 8);
    }
    f32x4 accy[4];
#pragma unroll
    for (int tj = 0; tj < 4; ++tj) accy[tj] = (f32x4)0.0f;
#pragma unroll
    for (int tj = 0; tj < 4; ++tj) {
        const int jr = tj * 16 + lr16;
        const int js = (jr >> 1) & 3;
        const f16x8 m0 = *(const f16x8*)(Ms + jr * 64 + (kb ^ js) * 8);
        const f16x8 m1 = *(const f16x8*)(Ms + jr * 64 + (4 + (kb ^ js)) * 8);
        const f16x8 v0 = *(const f16x8*)(Vt + jr * 64 + (kb ^ js) * 8);
        const f16x8 v1 = *(const f16x8*)(Vt + jr * 64 + (4 + (kb ^ js)) * 8);
        accy[tj] = __builtin_amdgcn_mfma_f32_16x16x32_f16(af[0],  m0, accy[tj], 0, 0, 0);
        accy[tj] = __builtin_amdgcn_mfma_f32_16x16x32_f16(af[1],  m1, accy[tj], 0, 0, 0);
        accy[tj] = __builtin_amdgcn_mfma_f32_16x16x32_f16(as2[0], v0, accy[tj], 0, 0, 0);
        accy[tj] = __builtin_amdgcn_mfma_f32_16x16x32_f16(as2[1], v1, accy[tj], 0, 0, 0);
    }
    f16* yo = y + ((size_t)b * SEQL + ch * 64) * DM + h * 64;
#pragma unroll
    for (int tj = 0; tj < 4; ++tj)
#pragma unroll
        for (int rr = 0; rr < 4; ++rr) {
            const int rc = w * 16 + kb * 4 + rr;
            yo[(size_t)rc * DM + tj * 16 + lr16] = (f16)accy[tj][rr];
        }
}

// ---------------- launch --------------------------------------------------------
extern "C" void kernel_launch(void* const* d_in, const int* in_sizes, int n_in,
                              void* d_out, int out_size, void* d_ws, size_t ws_size,
                              hipStream_t stream)
{
    const float* x      = (const float*)d_in[0];
    const float* norm_w = (const float*)d_in[1];
    const float* w_up   = (const float*)d_in[2];
    const float* w_gate = (const float*)d_in[3];
    const float* w_down = (const float*)d_in[4];
    const float* conv_w = (const float*)d_in[5];
    const float* conv_b = (const float*)d_in[6];
    const float* wq     = (const float*)d_in[7];
    const float* wk     = (const float*)d_in[8];
    const float* wv     = (const float*)d_in[9];
    const float* wo     = (const float*)d_in[10];
    float* out = (float*)d_out;

    const size_t BIG_NEED = 247463936ull;
    const bool big = ws_size >= BIG_NEED;

    if (big) {
        char* p = (char*)d_ws;
        f16* upg = (f16*)p;               p += (size_t)NRALL * 4096 * 2;
        f16* hb  = (f16*)p;               p += (size_t)NRALL * DM * 2;
        char* fmtD   = p;                 p += (size_t)64 * 1024 * 64;
        char* fmtQKV = p;                 p += (size_t)32 * 3072 * 64;
        char* fmtO   = p;                 p += (size_t)32 * 1024 * 64;
        f16* xn = (f16*)p;                p += (size_t)NRALL * DM * 2;
        char* fmtUG  = p;
        f16* G = (f16*)xn;                // overlays xn+fmtUG (dead after up/gate GEMM)
        f16* qkvb = upg;
        f16* yb   = hb;

        prep_k<<<NRALL + 640, 256, 0, stream>>>(x, norm_w, xn, w_up, w_gate, w_down,
                                                wq, wk, wv, wo, fmtUG, fmtD, fmtQKV, fmtO);

        mg256_k<0><<<16 * 64, 1024, 0, stream>>>(xn, DM, fmtUG, upg, 4096, DM, 16, nullptr);
        conv_gate_k<<<NRALL / 16, 256, 0, stream>>>(upg, conv_w, conv_b);
        mg256_k<0><<<4 * 64, 1024, 0, stream>>>(upg + 2048, 4096, fmtD, hb, 1024, DI, 4, nullptr);
        mg256_k<1><<<12 * 64, 1024, 0, stream>>>(hb, DM, fmtQKV, qkvb, 3072, DM, 12, nullptr);

        gscan_g_k<<<dim3(64, 16, 4), 256, 0, stream>>>(qkvb, G);
        gprefix_k<<<512, 256, 0, stream>>>(G);
        gscan_y_k<<<dim3(64, 16, 4), 256, 0, stream>>>(qkvb, G, yb);

        mg256_k<2><<<4 * 64, 1024, 0, stream>>>(yb, DM, fmtO, out, 1024, DM, 4, x);
    } else {
        // compact per-batch path
        char* p = (char*)d_ws;
        f16* xn = (f16*)p;                p += (size_t)NRALL * DM * 2;
        f16* upg = (f16*)p;               p += (size_t)SEQL * 4096 * 2;
        f16* hb  = (f16*)p;               p += (size_t)SEQL * DM * 2;
        f16* G = (f16*)p;                 p += (size_t)16 * 64 * 4096 * 2;
        char* fmtUG  = p;                 p += (size_t)32 * 4096 * 64;
        char* fmtD   = p;                 p += (size_t)64 * 1024 * 64;
        char* fmtQKV = p;                 p += (size_t)32 * 3072 * 64;
        char* fmtO   = p;
        f16* qkvb = upg;
        f16* yb   = hb;

        prep_k<<<NRALL + 640, 256, 0, stream>>>(x, norm_w, xn, w_up, w_gate, w_down,
                                                wq, wk, wv, wo, fmtUG, fmtD, fmtQKV, fmtO);

        for (int b = 0; b < 4; ++b) {
            const f16* xnb = xn + (size_t)b * SEQL * DM;
            mg256_k<0><<<16 * 16, 1024, 0, stream>>>(xnb, DM, fmtUG, upg, 4096, DM, 16, nullptr);
            conv_gate_k<<<SEQL / 16, 256, 0, stream>>>(upg, conv_w, conv_b);
            mg256_k<0><<<4 * 16, 1024, 0, stream>>>(upg + 2048, 4096, fmtD, hb, 1024, DI, 4, nullptr);
            mg256_k<1><<<12 * 16, 1024, 0, stream>>>(hb, DM, fmtQKV, qkvb, 3072, DM, 12, nullptr);
            gscan_g_k<<<dim3(64, 16, 1), 256, 0, stream>>>(qkvb, G);
            gprefix_k<<<128, 256, 0, stream>>>(G);
            gscan_y_k<<<dim3(64, 16, 1), 256, 0, stream>>>(qkvb, G, yb);
            mg256_k<2><<<4 * 16, 1024, 0, stream>>>(yb, DM, fmtO,
                                                    out + (size_t)b * SEQL * DM, 1024, DM, 4,
                                                    x + (size_t)b * SEQL * DM);
        }
    }
}

// Round 16
// 524.257 us; speedup vs baseline: 6.7190x; 1.0156x over previous
//
#include <hip/hip_runtime.h>
#include <hip/hip_fp16.h>
#include <cstdint>

// Problem constants (B=4, S=4096, D=1024)
#define NRALL 16384
#define DM    1024
#define DI    2048
#define SEQL  4096

typedef _Float16 f16;
typedef _Float16 f16x8 __attribute__((ext_vector_type(8)));
typedef _Float16 f16x4 __attribute__((ext_vector_type(4)));
typedef _Float16 f16x2 __attribute__((ext_vector_type(2)));
typedef float    f32x4 __attribute__((ext_vector_type(4)));

__device__ __forceinline__ float phi_f(float t)  { return t > 0.0f ? t + 1.0f : __expf(t); }
__device__ __forceinline__ float silu_f(float t) { return t / (1.0f + __expf(-t)); }

#define GLDS16(g, l)                                                            \
    __builtin_amdgcn_global_load_lds(                                           \
        (const __attribute__((address_space(1))) void*)(g),                     \
        (__attribute__((address_space(3))) void*)(l), 16, 0, 0)

// ---------------- 1. merged prep: rmsnorm rows + weight format ------------------
// ng = n*mul + off : UG uses mul=2 (up even cols, gate odd) so the GEMM tile has
// up[c] and gate[c] together for the fused conv epilogue.
__device__ __forceinline__ void wfmt_one(const float* __restrict__ W, char* __restrict__ fmt,
                                         int n, int kt, int Nw, int Ntot, int mul, int off)
{
    const int ng = n * mul + off;
#pragma unroll
    for (int kh = 0; kh < 2; ++kh) {
        char* o = fmt + ((size_t)(kt * 2 + kh) * Ntot + ng) * 64;
#pragma unroll
        for (int c2 = 0; c2 < 4; ++c2) {
            f16x8 p;
#pragma unroll
            for (int j = 0; j < 8; ++j)
                p[j] = (f16)W[(size_t)(kt * 64 + kh * 32 + c2 * 8 + j) * Nw + n];
            *(f16x8*)(o + ((c2 ^ ((ng >> 1) & 3)) << 4)) = p;
        }
    }
}

__global__ __launch_bounds__(256) void prep_k(const float* __restrict__ x,
                                              const float* __restrict__ nw,
                                              f16* __restrict__ xn,
                                              const float* __restrict__ w_up,
                                              const float* __restrict__ w_gate,
                                              const float* __restrict__ w_down,
                                              const float* __restrict__ wq,
                                              const float* __restrict__ wk,
                                              const float* __restrict__ wv,
                                              const float* __restrict__ wo,
                                              char* __restrict__ fmtUG,
                                              char* __restrict__ fmtD,
                                              char* __restrict__ fmtQKV,
                                              char* __restrict__ fmtO)
{
    const int t = threadIdx.x;
    if (blockIdx.x < NRALL) {
        const int r = blockIdx.x;
        const float4 v = *(const float4*)(x + (size_t)r * DM + t * 4);
        float s = v.x * v.x + v.y * v.y + v.z * v.z + v.w * v.w;
#pragma unroll
        for (int m = 1; m < 64; m <<= 1) s += __shfl_xor(s, m);
        __shared__ float ws4[4];
        if ((t & 63) == 0) ws4[t >> 6] = s;
        __syncthreads();
        const float tot = ws4[0] + ws4[1] + ws4[2] + ws4[3];
        const float sc = rsqrtf(tot * (1.0f / DM) + 1e-5f);
        const float4 w = *(const float4*)(nw + t * 4);
        f16x4 o;
        o[0] = (f16)(v.x * sc * w.x); o[1] = (f16)(v.y * sc * w.y);
        o[2] = (f16)(v.z * sc * w.z); o[3] = (f16)(v.w * sc * w.w);
        *(f16x4*)(xn + (size_t)r * DM + t * 4) = o;
        return;
    }
    int id = blockIdx.x - NRALL;
    if (id < 128) { wfmt_one(w_up,   fmtUG,  (id % 8) * 256 + t, id / 8, DI, 4096, 2, 0); return; }
    id -= 128;
    if (id < 128) { wfmt_one(w_gate, fmtUG,  (id % 8) * 256 + t, id / 8, DI, 4096, 2, 1); return; }
    id -= 128;
    if (id < 128) { wfmt_one(w_down, fmtD,   (id % 4) * 256 + t, id / 4, DM, 1024, 1, 0); return; }
    id -= 128;
    if (id < 64)  { wfmt_one(wq,     fmtQKV, (id % 4) * 256 + t, id / 4, DM, 3072, 1, 0);    return; }
    id -= 64;
    if (id < 64)  { wfmt_one(wk,     fmtQKV, (id % 4) * 256 + t, id / 4, DM, 3072, 1, 1024); return; }
    id -= 64;
    if (id < 64)  { wfmt_one(wv,     fmtQKV, (id % 4) * 256 + t, id / 4, DM, 3072, 1, 2048); return; }
    id -= 64;
    wfmt_one(wo, fmtO, (id % 4) * 256 + t, id / 4, DM, 1024, 1, 0);
}

// ---------------- 2. 256x256 MFMA GEMM, 16 waves (4m x 4n), 8-phase -------------
// EPI: 0 f16 out; 1 qkv epilogue (phi ranges); 2 +addx fp32 out;
//      3 fused conv+silu+gate (UG interleaved tile -> val[.][2048]) + boundary dumps.
#define PH(p, ks, mh, STAGE_STMT)                                                 \
    {                                                                             \
        if ((mh) == 0) {                                                          \
            _Pragma("unroll")                                                     \
            for (int q = 0; q < 2; ++q) {                                         \
                const int row = wm * 64 + q * 16 + lr16;                          \
                af[q] = *(const f16x8*)(ldsb + (p) * 32768 + (ks) * 16384         \
                        + row * 64 + ((kb ^ ((row >> 1) & 3)) << 4));             \
            }                                                                     \
            _Pragma("unroll")                                                     \
            for (int q = 0; q < 4; ++q) {                                         \
                const int n = wn * 64 + q * 16 + lr16;                            \
                bf[q] = *(const f16x8*)(ldsb + 65536 + (p) * 32768 + (ks) * 16384 \
                        + n * 64 + ((kb ^ ((n >> 1) & 3)) << 4));                 \
            }                                                                     \
        } else {                                                                  \
            _Pragma("unroll")                                                     \
            for (int q = 0; q < 2; ++q) {                                         \
                const int row = wm * 64 + (q + 2) * 16 + lr16;                    \
                af[2 + q] = *(const f16x8*)(ldsb + (p) * 32768 + (ks) * 16384     \
                            + row * 64 + ((kb ^ ((row >> 1) & 3)) << 4));         \
            }                                                                     \
        }                                                                         \
        STAGE_STMT;                                                               \
        asm volatile("s_waitcnt vmcnt(3)" ::: "memory");                          \
        __builtin_amdgcn_sched_barrier(0);                                        \
        __builtin_amdgcn_s_barrier();                                             \
        asm volatile("s_waitcnt lgkmcnt(0)" ::: "memory");                        \
        __builtin_amdgcn_sched_barrier(0);                                        \
        __builtin_amdgcn_s_setprio(1);                                            \
        _Pragma("unroll")                                                         \
        for (int q = 0; q < 2; ++q) {                                             \
            acc[(mh) * 2 + q][0] = __builtin_amdgcn_mfma_f32_16x16x32_f16(        \
                af[(mh) * 2 + q], bf[0], acc[(mh) * 2 + q][0], 0, 0, 0);          \
            acc[(mh) * 2 + q][1] = __builtin_amdgcn_mfma_f32_16x16x32_f16(        \
                af[(mh) * 2 + q], bf[1], acc[(mh) * 2 + q][1], 0, 0, 0);          \
            acc[(mh) * 2 + q][2] = __builtin_amdgcn_mfma_f32_16x16x32_f16(        \
                af[(mh) * 2 + q], bf[2], acc[(mh) * 2 + q][2], 0, 0, 0);          \
            acc[(mh) * 2 + q][3] = __builtin_amdgcn_mfma_f32_16x16x32_f16(        \
                af[(mh) * 2 + q], bf[3], acc[(mh) * 2 + q][3], 0, 0, 0);          \
        }                                                                         \
        __builtin_amdgcn_s_setprio(0);                                            \
        __builtin_amdgcn_sched_barrier(0);                                        \
    }

template <int EPI>
__global__ __launch_bounds__(1024) void mg256_k(const f16* __restrict__ A, int lda,
                                                const char* __restrict__ fmt,
                                                void* __restrict__ Cv,
                                                int N, int K, int gx,
                                                const float* __restrict__ addx,
                                                const float* __restrict__ cw = nullptr,
                                                const float* __restrict__ cb = nullptr,
                                                f16* __restrict__ tailb = nullptr)
{
    __shared__ __align__(16) char ldsb[131072];

    const int t = threadIdx.x;
    int wid = blockIdx.x;
    { const int cpx = gridDim.x >> 3; wid = (wid & 7) * cpx + (wid >> 3); }  // XCD swizzle
    const int bx = wid % gx, by = wid / gx;
    const int bm = by * 256, bn = bx * 256;
    const int lane = t & 63, wv = t >> 6;
    const int wm = wv >> 2, wn = wv & 3;
    const int kb = lane >> 4, lr16 = lane & 15;
    const int NT = K >> 6;

    f32x4 acc[4][4];
#pragma unroll
    for (int i = 0; i < 4; ++i)
#pragma unroll
        for (int j = 0; j < 4; ++j) acc[i][j] = (f32x4)0.0f;

    const int arow = t >> 2;
    const int ac2 = (t & 3) ^ ((arow >> 1) & 3);
    const f16* Abase = A + (size_t)(bm + arow) * lda + ac2 * 8;
    const char* Bbase = fmt + (size_t)bn * 64 + (size_t)t * 16;
    const size_t BKstep = (size_t)N * 64;
    char* ldsT = ldsb + t * 16;

    auto STAGE_A = [&](int p, int kh, int kt) {
        GLDS16(Abase + kt * 64 + kh * 32, ldsT + p * 32768 + kh * 16384);
    };
    auto STAGE_B = [&](int p, int kh, int kt) {
        GLDS16(Bbase + (size_t)(kt * 2 + kh) * BKstep, ldsT + 65536 + p * 32768 + kh * 16384);
    };

    f16x8 af[4], bf[4];

    const int T1 = NT > 1 ? 1 : 0;
    STAGE_B(0, 0, 0); STAGE_A(0, 0, 0);
    STAGE_B(0, 1, 0); STAGE_A(0, 1, 0);
    STAGE_B(1, 0, T1); STAGE_A(1, 0, T1);
    asm volatile("s_waitcnt vmcnt(4)" ::: "memory");
    __builtin_amdgcn_s_barrier();
    __builtin_amdgcn_sched_barrier(0);

    const int NI = NT >> 1;
    for (int i = 0; i < NI; ++i) {
        const int tA = 2 * i + 1 < NT ? 2 * i + 1 : NT - 1;
        const int tB = 2 * i + 2 < NT ? 2 * i + 2 : NT - 1;
        const int tC = 2 * i + 3 < NT ? 2 * i + 3 : NT - 1;
        PH(0, 0, 0, STAGE_B(1, 1, tA))
        PH(0, 0, 1, STAGE_A(1, 1, tA))
        PH(0, 1, 0, STAGE_B(0, 0, tB))
        PH(0, 1, 1, STAGE_A(0, 0, tB))
        PH(1, 0, 0, STAGE_B(0, 1, tB))
        PH(1, 0, 1, STAGE_A(0, 1, tB))
        PH(1, 1, 0, STAGE_B(1, 0, tC))
        PH(1, 1, 1, STAGE_A(1, 0, tC))
    }
    asm volatile("s_waitcnt vmcnt(0)" ::: "memory");

    if (EPI == 3) {
        // ---- fused conv epilogue: acc tile -> LDS (up/gate split), conv+gate, val out
        __syncthreads();                    // all loop-phase LDS reads retired
        f16* upT = (f16*)ldsb;              // [256][128]
        f16* gtT = (f16*)(ldsb + 65536);    // [256][128]
#pragma unroll
        for (int fm = 0; fm < 4; ++fm) {
            const int row = wm * 64 + fm * 16 + kb * 4;
#pragma unroll
            for (int fn = 0; fn < 4; ++fn) {
                const int col = wn * 64 + fn * 16 + lr16;
                f16* dst = (col & 1) ? gtT : upT;
                const int c = col >> 1;
#pragma unroll
                for (int r = 0; r < 4; ++r)
                    dst[(row + r) * 128 + c] = (f16)acc[fm][fn][r];
            }
        }
        __syncthreads();
        const int c = t & 127, rg = t >> 7;       // col, row-group (8 x 32 rows)
        const int cg = bx * 128 + c;              // global conv channel
        const float4 tp = *(const float4*)(cw + (size_t)cg * 4);
        const float bias = cb[cg];
        const int r0 = rg * 32;
        float w0 = 0.f, w1 = 0.f, w2 = 0.f;       // zeros correct iff seq-start band
        if (r0 > 0) {
            w0 = (float)upT[(r0 - 3) * 128 + c];
            w1 = (float)upT[(r0 - 2) * 128 + c];
            w2 = (float)upT[(r0 - 1) * 128 + c];
        }
        f16* vout = (f16*)Cv;
#pragma unroll 8
        for (int i = 0; i < 32; ++i) {
            const int r = r0 + i;
            const float u = (float)upT[r * 128 + c];
            const float g = (float)gtT[r * 128 + c];
            float a = bias;
            a = fmaf(w0, tp.x, a); a = fmaf(w1, tp.y, a);
            a = fmaf(w2, tp.z, a); a = fmaf(u, tp.w, a);
            vout[(size_t)(bm + r) * 2048 + cg] = (f16)(silu_f(g) * silu_f(a));
            w0 = w1; w1 = w2; w2 = u;
        }
        const int band = bm >> 8;
        if (rg == 0) {                            // boundary dumps for fixup
#pragma unroll
            for (int i = 0; i < 3; ++i) {
                tailb[((size_t)band * 9 + i) * 2048 + cg]     = upT[i * 128 + c];
                tailb[((size_t)band * 9 + 6 + i) * 2048 + cg] = gtT[i * 128 + c];
            }
        } else if (rg == 7) {
#pragma unroll
            for (int i = 0; i < 3; ++i)
                tailb[((size_t)band * 9 + 3 + i) * 2048 + cg] = upT[(253 + i) * 128 + c];
        }
        return;
    }

#pragma unroll
    for (int fm = 0; fm < 4; ++fm) {
        const int row0 = bm + wm * 64 + fm * 16 + kb * 4;
#pragma unroll
        for (int fn = 0; fn < 4; ++fn) {
            const int col = bn + wn * 64 + fn * 16 + lr16;
#pragma unroll
            for (int r = 0; r < 4; ++r) {
                float o = acc[fm][fn][r];
                if (EPI == 1) {
                    if (col < DM) o = phi_f(o) * 0.125f;
                    else if (col < 2 * DM) o = phi_f(o);
                }
                if (EPI == 2) {
                    ((float*)Cv)[(size_t)(row0 + r) * N + col] =
                        o + addx[(size_t)(row0 + r) * N + col];
                } else {
                    ((f16*)Cv)[(size_t)(row0 + r) * N + col] = (f16)o;
                }
            }
        }
    }
}

// ---------------- 3. conv boundary fixup: rows 0..2 of non-seq-start bands ------
__global__ __launch_bounds__(256) void fixconv_k(const f16* __restrict__ tailb,
                                                 f16* __restrict__ val,
                                                 const float* __restrict__ cw,
                                                 const float* __restrict__ cb)
{
    const int b = blockIdx.x;
    if ((b & 15) == 0) return;                    // sequence-start band: already exact
    const int c0 = threadIdx.x * 8;
    float um[3][8], u[3][8], g[3][8];
#pragma unroll
    for (int i = 0; i < 3; ++i) {
        const f16x8 a  = *(const f16x8*)(tailb + ((size_t)(b - 1) * 9 + 3 + i) * 2048 + c0);
        const f16x8 bb = *(const f16x8*)(tailb + ((size_t)b * 9 + i) * 2048 + c0);
        const f16x8 gg = *(const f16x8*)(tailb + ((size_t)b * 9 + 6 + i) * 2048 + c0);
#pragma unroll
        for (int j = 0; j < 8; ++j) {
            um[i][j] = (float)a[j]; u[i][j] = (float)bb[j]; g[i][j] = (float)gg[j];
        }
    }
#pragma unroll
    for (int r = 0; r < 3; ++r) {
        f16x8 o;
#pragma unroll
        for (int j = 0; j < 8; ++j) {
            const int cg = c0 + j;
            const float4 tp = *(const float4*)(cw + (size_t)cg * 4);
            float a = cb[cg];
            const float wnd[6] = {um[0][j], um[1][j], um[2][j], u[0][j], u[1][j], u[2][j]};
            a = fmaf(wnd[r],     tp.x, a);
            a = fmaf(wnd[r + 1], tp.y, a);
            a = fmaf(wnd[r + 2], tp.z, a);
            a = fmaf(wnd[r + 3], tp.w, a);
            o[j] = (f16)(silu_f(g[r][j]) * silu_f(a));
        }
        *(f16x8*)(val + ((size_t)b * 256 + r) * 2048 + c0) = o;
    }
}

// ---------------- 4a. per-chunk outer products: GT[b][h][ch][e][d] = (K^T V)^T --
__global__ __launch_bounds__(256) void gscan_g_k(const f16* __restrict__ qkv,
                                                 f16* __restrict__ GT)
{
    __shared__ float Ks[4096];
    __shared__ float Vs[4096];
    const int t = threadIdx.x, ch = blockIdx.x, h = blockIdx.y, b = blockIdx.z;
    const int r = t >> 2, c16 = (t & 3) * 16;
    const f16* kp = qkv + ((size_t)b * SEQL + ch * 64 + r) * 3072 + DM + h * 64 + c16;
#pragma unroll
    for (int i = 0; i < 2; ++i) {
        const f16x8 kv = *(const f16x8*)(kp + 8 * i);
        const f16x8 vv = *(const f16x8*)(kp + DM + 8 * i);
#pragma unroll
        for (int j = 0; j < 8; ++j) {
            Ks[r * 64 + c16 + 8 * i + j] = (float)kv[j];
            Vs[r * 64 + c16 + 8 * i + j] = (float)vv[j];
        }
    }
    __syncthreads();
    const int e4 = (t >> 4) * 4, d4 = (t & 15) * 4;
    float4 ag[4] = {};
#pragma unroll 4
    for (int c = 0; c < 64; ++c) {
        float va[4];
        *(float4*)va = *(const float4*)(Vs + c * 64 + e4);
        const float4 ka = *(const float4*)(Ks + c * 64 + d4);
        ag[0].x = fmaf(va[0], ka.x, ag[0].x); ag[0].y = fmaf(va[0], ka.y, ag[0].y);
        ag[0].z = fmaf(va[0], ka.z, ag[0].z); ag[0].w = fmaf(va[0], ka.w, ag[0].w);
        ag[1].x = fmaf(va[1], ka.x, ag[1].x); ag[1].y = fmaf(va[1], ka.y, ag[1].y);
        ag[1].z = fmaf(va[1], ka.z, ag[1].z); ag[1].w = fmaf(va[1], ka.w, ag[1].w);
        ag[2].x = fmaf(va[2], ka.x, ag[2].x); ag[2].y = fmaf(va[2], ka.y, ag[2].y);
        ag[2].z = fmaf(va[2], ka.z, ag[2].z); ag[2].w = fmaf(va[2], ka.w, ag[2].w);
        ag[3].x = fmaf(va[3], ka.x, ag[3].x); ag[3].y = fmaf(va[3], ka.y, ag[3].y);
        ag[3].z = fmaf(va[3], ka.z, ag[3].z); ag[3].w = fmaf(va[3], ka.w, ag[3].w);
    }
    f16* go = GT + (((size_t)b * 16 + h) * 64 + ch) * 4096 + e4 * 64 + d4;
#pragma unroll
    for (int i = 0; i < 4; ++i) {
        f16x4 o;
        o[0] = (f16)ag[i].x; o[1] = (f16)ag[i].y;
        o[2] = (f16)ag[i].z; o[3] = (f16)ag[i].w;
        *(f16x4*)(go + i * 64) = o;
    }
}

// ---------------- 4b. in-place exclusive prefix over chunks (f16x2, fp32 carry) -
__global__ __launch_bounds__(256) void gprefix_k(f16* __restrict__ G)
{
    const int bh = blockIdx.x >> 3, sl = blockIdx.x & 7;
    f16x2* p = (f16x2*)(G + (size_t)bh * 64 * 4096) + sl * 256 + threadIdx.x;
    float r0 = 0.0f, r1 = 0.0f;
#pragma unroll 4
    for (int ch = 0; ch < 64; ++ch) {
        const f16x2 g = *p;
        f16x2 o; o[0] = (f16)r0; o[1] = (f16)r1;
        *p = o;
        r0 += (float)g[0]; r1 += (float)g[1];
        p += 2048;
    }
}

// ---------------- 4c. per-chunk read via MFMA: y = q*M_excl + tril(q k^T) v -----
__global__ __launch_bounds__(256) void gscan_y_k(const f16* __restrict__ qkv,
                                                 const f16* __restrict__ GT,
                                                 f16* __restrict__ y)
{
    __shared__ __align__(16) char lds[40960];
    f16* Qs = (f16*)lds;
    f16* Ks = (f16*)(lds + 8192);
    f16* Ms = (f16*)(lds + 16384);
    f16* Vt = (f16*)(lds + 24576);
    f16* Ss = (f16*)(lds + 32768);

    const int t = threadIdx.x, ch = blockIdx.x, h = blockIdx.y, b = blockIdx.z;
    const int lane = t & 63, w = t >> 6;
    const int kb = lane >> 4, lr16 = lane & 15;

    const int r = t >> 2;
    const int c0 = (t & 3) * 2;
    const int rkey = (r >> 1) & 3;
    const f16* qp = qkv + ((size_t)b * SEQL + ch * 64 + r) * 3072 + h * 64;
    const f16* mp = GT + (((size_t)b * 16 + h) * 64 + ch) * 4096 + r * 64;
#pragma unroll
    for (int cc = 0; cc < 2; ++cc) {
        const int c = c0 + cc;
        const int sw = c ^ rkey;
        const f16x8 qv = *(const f16x8*)(qp + c * 8);
        const f16x8 kv = *(const f16x8*)(qp + DM + c * 8);
        const f16x8 vv = *(const f16x8*)(qp + 2 * DM + c * 8);
        const f16x8 mv = *(const f16x8*)(mp + c * 8);
        *(f16x8*)(Qs + r * 64 + sw * 8) = qv;
        *(f16x8*)(Ks + r * 64 + sw * 8) = kv;
        *(f16x8*)(Ms + r * 64 + sw * 8) = mv;
#pragma unroll
        for (int jj = 0; jj < 8; ++jj) {
            const int j = c * 8 + jj;
            Vt[j * 64 + ((((r >> 3) ^ ((j >> 1) & 3)) << 3) + (r & 7))] = vv[jj];
        }
    }
    __syncthreads();

    f16x8 af[2];
    {
        const int row = w * 16 + lr16;
        const int sz = (row >> 1) & 3;
        af[0] = *(const f16x8*)(Qs + row * 64 + (kb ^ sz) * 8);
        af[1] = *(const f16x8*)(Qs + row * 64 + (4 + (kb ^ sz)) * 8);
    }
    f32x4 accs[4];
#pragma unroll
    for (int te = 0; te < 4; ++te) accs[te] = (f32x4)0.0f;
#pragma unroll
    for (int te = 0; te < 4; ++te) {
        const int er = te * 16 + lr16;
        const int es = (er >> 1) & 3;
        const f16x8 b0 = *(const f16x8*)(Ks + er * 64 + (kb ^ es) * 8);
        const f16x8 b1 = *(const f16x8*)(Ks + er * 64 + (4 + (kb ^ es)) * 8);
        accs[te] = __builtin_amdgcn_mfma_f32_16x16x32_f16(af[0], b0, accs[te], 0, 0, 0);
        accs[te] = __builtin_amdgcn_mfma_f32_16x16x32_f16(af[1], b1, accs[te], 0, 0, 0);
    }
#pragma unroll
    for (int te = 0; te < 4; ++te)
#pragma unroll
        for (int rr = 0; rr < 4; ++rr) {
            const int rc = w * 16 + kb * 4 + rr;
            const int ce = te * 16 + lr16;
            const float v = (ce <= rc) ? accs[te][rr] : 0.0f;
            Ss[rc * 64 + ((((ce >> 3) ^ ((rc >> 1) & 3)) << 3) + (ce & 7))] = (f16)v;
        }
    __syncthreads();

    f16x8 as2[2];
    {
        const int row = w * 16 + lr16;
        const int sz = (row >> 1) & 3;
        as2[0] = *(const f16x8*)(Ss + row * 64 + (kb ^ sz) * 8);
        as2[1] = *(const f16x8*)(Ss + row * 64 + (4 + (kb ^ sz)) * 8);
    }
    f32x4 accy[4];
#pragma unroll
    for (int tj = 0; tj < 4; ++tj) accy[tj] = (f32x4)0.0f;
#pragma unroll
    for (int tj = 0; tj < 4; ++tj) {
        const int jr = tj * 16 + lr16;
        const int js = (jr >> 1) & 3;
        const f16x8 m0 = *(const f16x8*)(Ms + jr * 64 + (kb ^ js) * 8);
        const f16x8 m1 = *(const f16x8*)(Ms + jr * 64 + (4 + (kb ^ js)) * 8);
        const f16x8 v0 = *(const f16x8*)(Vt + jr * 64 + (kb ^ js) * 8);
        const f16x8 v1 = *(const f16x8*)(Vt + jr * 64 + (4 + (kb ^ js)) * 8);
        accy[tj] = __builtin_amdgcn_mfma_f32_16x16x32_f16(af[0],  m0, accy[tj], 0, 0, 0);
        accy[tj] = __builtin_amdgcn_mfma_f32_16x16x32_f16(af[1],  m1, accy[tj], 0, 0, 0);
        accy[tj] = __builtin_amdgcn_mfma_f32_16x16x32_f16(as2[0], v0, accy[tj], 0, 0, 0);
        accy[tj] = __builtin_amdgcn_mfma_f32_16x16x32_f16(as2[1], v1, accy[tj], 0, 0, 0);
    }
    f16* yo = y + ((size_t)b * SEQL + ch * 64) * DM + h * 64;
#pragma unroll
    for (int tj = 0; tj < 4; ++tj)
#pragma unroll
        for (int rr = 0; rr < 4; ++rr) {
            const int rc = w * 16 + kb * 4 + rr;
            yo[(size_t)rc * DM + tj * 16 + lr16] = (f16)accy[tj][rr];
        }
}

// ---------------- launch --------------------------------------------------------
extern "C" void kernel_launch(void* const* d_in, const int* in_sizes, int n_in,
                              void* d_out, int out_size, void* d_ws, size_t ws_size,
                              hipStream_t stream)
{
    const float* x      = (const float*)d_in[0];
    const float* norm_w = (const float*)d_in[1];
    const float* w_up   = (const float*)d_in[2];
    const float* w_gate = (const float*)d_in[3];
    const float* w_down = (const float*)d_in[4];
    const float* conv_w = (const float*)d_in[5];
    const float* conv_b = (const float*)d_in[6];
    const float* wq     = (const float*)d_in[7];
    const float* wk     = (const float*)d_in[8];
    const float* wv     = (const float*)d_in[9];
    const float* wo     = (const float*)d_in[10];
    float* out = (float*)d_out;

    const size_t BIG_NEED = 247463936ull;
    const bool big = ws_size >= BIG_NEED;

    if (big) {
        // layout (246.3 MB): val 64 | qkv 96 | hb 32 | fmtD 4 | fmtQKV 6 | fmtO 2 |
        //                    tail 2.25 | xn 32 | fmtUG 8 ; G (33.5) overlays xn+fmtUG
        char* p = (char*)d_ws;
        f16* val = (f16*)p;               p += (size_t)NRALL * 2048 * 2;
        f16* qkvb = (f16*)p;              p += (size_t)NRALL * 3072 * 2;
        f16* hb  = (f16*)p;               p += (size_t)NRALL * DM * 2;
        char* fmtD   = p;                 p += (size_t)64 * 1024 * 64;
        char* fmtQKV = p;                 p += (size_t)32 * 3072 * 64;
        char* fmtO   = p;                 p += (size_t)32 * 1024 * 64;
        f16* tailb = (f16*)p;             p += (size_t)64 * 9 * 2048 * 2;
        f16* xn = (f16*)p;                p += (size_t)NRALL * DM * 2;
        char* fmtUG  = p;
        f16* G = (f16*)xn;
        f16* yb = hb;

        prep_k<<<NRALL + 640, 256, 0, stream>>>(x, norm_w, xn, w_up, w_gate, w_down,
                                                wq, wk, wv, wo, fmtUG, fmtD, fmtQKV, fmtO);

        mg256_k<3><<<16 * 64, 1024, 0, stream>>>(xn, DM, fmtUG, val, 4096, DM, 16, nullptr,
                                                 conv_w, conv_b, tailb);
        fixconv_k<<<64, 256, 0, stream>>>(tailb, val, conv_w, conv_b);
        mg256_k<0><<<4 * 64, 1024, 0, stream>>>(val, 2048, fmtD, hb, 1024, DI, 4, nullptr);
        mg256_k<1><<<12 * 64, 1024, 0, stream>>>(hb, DM, fmtQKV, qkvb, 3072, DM, 12, nullptr);

        gscan_g_k<<<dim3(64, 16, 4), 256, 0, stream>>>(qkvb, G);
        gprefix_k<<<512, 256, 0, stream>>>(G);
        gscan_y_k<<<dim3(64, 16, 4), 256, 0, stream>>>(qkvb, G, yb);

        mg256_k<2><<<4 * 64, 1024, 0, stream>>>(yb, DM, fmtO, out, 1024, DM, 4, x);
    } else {
        // compact per-batch path (~109 MB)
        char* p = (char*)d_ws;
        f16* xn = (f16*)p;                p += (size_t)NRALL * DM * 2;
        f16* val = (f16*)p;               p += (size_t)SEQL * 2048 * 2;
        f16* qkvb = (f16*)p;              p += (size_t)SEQL * 3072 * 2;
        f16* hb  = (f16*)p;               p += (size_t)SEQL * DM * 2;
        f16* G = (f16*)p;                 p += (size_t)16 * 64 * 4096 * 2;
        char* fmtUG  = p;                 p += (size_t)32 * 4096 * 64;
        char* fmtD   = p;                 p += (size_t)64 * 1024 * 64;
        char* fmtQKV = p;                 p += (size_t)32 * 3072 * 64;
        char* fmtO   = p;                 p += (size_t)32 * 1024 * 64;
        f16* tailb = (f16*)p;
        f16* yb = hb;

        prep_k<<<NRALL + 640, 256, 0, stream>>>(x, norm_w, xn, w_up, w_gate, w_down,
                                                wq, wk, wv, wo, fmtUG, fmtD, fmtQKV, fmtO);

        for (int b = 0; b < 4; ++b) {
            const f16* xnb = xn + (size_t)b * SEQL * DM;
            mg256_k<3><<<16 * 16, 1024, 0, stream>>>(xnb, DM, fmtUG, val, 4096, DM, 16, nullptr,
                                                     conv_w, conv_b, tailb);
            fixconv_k<<<16, 256, 0, stream>>>(tailb, val, conv_w, conv_b);
            mg256_k<0><<<4 * 16, 1024, 0, stream>>>(val, 2048, fmtD, hb, 1024, DI, 4, nullptr);
            mg256_k<1><<<12 * 16, 1024, 0, stream>>>(hb, DM, fmtQKV, qkvb, 3072, DM, 12, nullptr);
            gscan_g_k<<<dim3(64, 16, 1), 256, 0, stream>>>(qkvb, G);
            gprefix_k<<<128, 256, 0, stream>>>(G);
            gscan_y_k<<<dim3(64, 16, 1), 256, 0, stream>>>(qkvb, G, yb);
            mg256_k<2><<<4 * 16, 1024, 0, stream>>>(yb, DM, fmtO,
                                                    out + (size_t)b * SEQL * DM, 1024, DM, 4,
                                                    x + (size_t)b * SEQL * DM);
        }
    }
}

// Round 17
// 518.426 us; speedup vs baseline: 6.7946x; 1.0112x over previous
//
#include <hip/hip_runtime.h>
#include <hip/hip_fp16.h>
#include <cstdint>

// Problem constants (B=4, S=4096, D=1024)
#define NRALL 16384
#define DM    1024
#define DI    2048
#define SEQL  4096

typedef _Float16 f16;
typedef _Float16 f16x8 __attribute__((ext_vector_type(8)));
typedef _Float16 f16x4 __attribute__((ext_vector_type(4)));
typedef _Float16 f16x2 __attribute__((ext_vector_type(2)));
typedef float    f32x4 __attribute__((ext_vector_type(4)));

__device__ __forceinline__ float phi_f(float t)  { return t > 0.0f ? t + 1.0f : __expf(t); }
__device__ __forceinline__ float silu_f(float t) { return t / (1.0f + __expf(-t)); }

#define GLDS16(g, l)                                                            \
    __builtin_amdgcn_global_load_lds(                                           \
        (const __attribute__((address_space(1))) void*)(g),                     \
        (__attribute__((address_space(3))) void*)(l), 16, 0, 0)

// epilogue tile index: XOR column with row-derived key -> kb groups hit disjoint
// bank sets (fixes the 6.3M-conflict hot spot of the fused conv epilogue)
#define CSWZ(row, c) ((row) * 128 + ((c) ^ ((((row) >> 2) & 7) << 3)))

// ---------------- 1. merged prep: rmsnorm rows + weight format ------------------
// ng = n*mul + off : UG uses mul=2 (up even cols, gate odd) so the GEMM tile has
// up[c] and gate[c] together for the fused conv epilogue.
__device__ __forceinline__ void wfmt_one(const float* __restrict__ W, char* __restrict__ fmt,
                                         int n, int kt, int Nw, int Ntot, int mul, int off)
{
    const int ng = n * mul + off;
#pragma unroll
    for (int kh = 0; kh < 2; ++kh) {
        char* o = fmt + ((size_t)(kt * 2 + kh) * Ntot + ng) * 64;
#pragma unroll
        for (int c2 = 0; c2 < 4; ++c2) {
            f16x8 p;
#pragma unroll
            for (int j = 0; j < 8; ++j)
                p[j] = (f16)W[(size_t)(kt * 64 + kh * 32 + c2 * 8 + j) * Nw + n];
            *(f16x8*)(o + ((c2 ^ ((ng >> 1) & 3)) << 4)) = p;
        }
    }
}

__global__ __launch_bounds__(256) void prep_k(const float* __restrict__ x,
                                              const float* __restrict__ nw,
                                              f16* __restrict__ xn,
                                              const float* __restrict__ w_up,
                                              const float* __restrict__ w_gate,
                                              const float* __restrict__ w_down,
                                              const float* __restrict__ wq,
                                              const float* __restrict__ wk,
                                              const float* __restrict__ wv,
                                              const float* __restrict__ wo,
                                              char* __restrict__ fmtUG,
                                              char* __restrict__ fmtD,
                                              char* __restrict__ fmtQKV,
                                              char* __restrict__ fmtO)
{
    const int t = threadIdx.x;
    if (blockIdx.x < NRALL) {
        const int r = blockIdx.x;
        const float4 v = *(const float4*)(x + (size_t)r * DM + t * 4);
        float s = v.x * v.x + v.y * v.y + v.z * v.z + v.w * v.w;
#pragma unroll
        for (int m = 1; m < 64; m <<= 1) s += __shfl_xor(s, m);
        __shared__ float ws4[4];
        if ((t & 63) == 0) ws4[t >> 6] = s;
        __syncthreads();
        const float tot = ws4[0] + ws4[1] + ws4[2] + ws4[3];
        const float sc = rsqrtf(tot * (1.0f / DM) + 1e-5f);
        const float4 w = *(const float4*)(nw + t * 4);
        f16x4 o;
        o[0] = (f16)(v.x * sc * w.x); o[1] = (f16)(v.y * sc * w.y);
        o[2] = (f16)(v.z * sc * w.z); o[3] = (f16)(v.w * sc * w.w);
        *(f16x4*)(xn + (size_t)r * DM + t * 4) = o;
        return;
    }
    int id = blockIdx.x - NRALL;
    if (id < 128) { wfmt_one(w_up,   fmtUG,  (id % 8) * 256 + t, id / 8, DI, 4096, 2, 0); return; }
    id -= 128;
    if (id < 128) { wfmt_one(w_gate, fmtUG,  (id % 8) * 256 + t, id / 8, DI, 4096, 2, 1); return; }
    id -= 128;
    if (id < 128) { wfmt_one(w_down, fmtD,   (id % 4) * 256 + t, id / 4, DM, 1024, 1, 0); return; }
    id -= 128;
    if (id < 64)  { wfmt_one(wq,     fmtQKV, (id % 4) * 256 + t, id / 4, DM, 3072, 1, 0);    return; }
    id -= 64;
    if (id < 64)  { wfmt_one(wk,     fmtQKV, (id % 4) * 256 + t, id / 4, DM, 3072, 1, 1024); return; }
    id -= 64;
    if (id < 64)  { wfmt_one(wv,     fmtQKV, (id % 4) * 256 + t, id / 4, DM, 3072, 1, 2048); return; }
    id -= 64;
    wfmt_one(wo, fmtO, (id % 4) * 256 + t, id / 4, DM, 1024, 1, 0);
}

// ---------------- 2. 256x256 MFMA GEMM, 16 waves (4m x 4n), 8-phase -------------
// EPI: 0 f16 out; 1 qkv epilogue (phi ranges); 2 +addx fp32 out;
//      3 fused conv+silu+gate (UG interleaved tile -> val[.][2048]) + boundary dumps.
#define PH(p, ks, mh, STAGE_STMT)                                                 \
    {                                                                             \
        if ((mh) == 0) {                                                          \
            _Pragma("unroll")                                                     \
            for (int q = 0; q < 2; ++q) {                                         \
                const int row = wm * 64 + q * 16 + lr16;                          \
                af[q] = *(const f16x8*)(ldsb + (p) * 32768 + (ks) * 16384         \
                        + row * 64 + ((kb ^ ((row >> 1) & 3)) << 4));             \
            }                                                                     \
            _Pragma("unroll")                                                     \
            for (int q = 0; q < 4; ++q) {                                         \
                const int n = wn * 64 + q * 16 + lr16;                            \
                bf[q] = *(const f16x8*)(ldsb + 65536 + (p) * 32768 + (ks) * 16384 \
                        + n * 64 + ((kb ^ ((n >> 1) & 3)) << 4));                 \
            }                                                                     \
        } else {                                                                  \
            _Pragma("unroll")                                                     \
            for (int q = 0; q < 2; ++q) {                                         \
                const int row = wm * 64 + (q + 2) * 16 + lr16;                    \
                af[2 + q] = *(const f16x8*)(ldsb + (p) * 32768 + (ks) * 16384     \
                            + row * 64 + ((kb ^ ((row >> 1) & 3)) << 4));         \
            }                                                                     \
        }                                                                         \
        STAGE_STMT;                                                               \
        asm volatile("s_waitcnt vmcnt(3)" ::: "memory");                          \
        __builtin_amdgcn_sched_barrier(0);                                        \
        __builtin_amdgcn_s_barrier();                                             \
        asm volatile("s_waitcnt lgkmcnt(0)" ::: "memory");                        \
        __builtin_amdgcn_sched_barrier(0);                                        \
        __builtin_amdgcn_s_setprio(1);                                            \
        _Pragma("unroll")                                                         \
        for (int q = 0; q < 2; ++q) {                                             \
            acc[(mh) * 2 + q][0] = __builtin_amdgcn_mfma_f32_16x16x32_f16(        \
                af[(mh) * 2 + q], bf[0], acc[(mh) * 2 + q][0], 0, 0, 0);          \
            acc[(mh) * 2 + q][1] = __builtin_amdgcn_mfma_f32_16x16x32_f16(        \
                af[(mh) * 2 + q], bf[1], acc[(mh) * 2 + q][1], 0, 0, 0);          \
            acc[(mh) * 2 + q][2] = __builtin_amdgcn_mfma_f32_16x16x32_f16(        \
                af[(mh) * 2 + q], bf[2], acc[(mh) * 2 + q][2], 0, 0, 0);          \
            acc[(mh) * 2 + q][3] = __builtin_amdgcn_mfma_f32_16x16x32_f16(        \
                af[(mh) * 2 + q], bf[3], acc[(mh) * 2 + q][3], 0, 0, 0);          \
        }                                                                         \
        __builtin_amdgcn_s_setprio(0);                                            \
        __builtin_amdgcn_sched_barrier(0);                                        \
    }

template <int EPI>
__global__ __launch_bounds__(1024) void mg256_k(const f16* __restrict__ A, int lda,
                                                const char* __restrict__ fmt,
                                                void* __restrict__ Cv,
                                                int N, int K, int gx,
                                                const float* __restrict__ addx,
                                                const float* __restrict__ cw = nullptr,
                                                const float* __restrict__ cb = nullptr,
                                                f16* __restrict__ tailb = nullptr)
{
    __shared__ __align__(16) char ldsb[131072];

    const int t = threadIdx.x;
    int wid = blockIdx.x;
    { const int cpx = gridDim.x >> 3; wid = (wid & 7) * cpx + (wid >> 3); }  // XCD swizzle
    const int bx = wid % gx, by = wid / gx;
    const int bm = by * 256, bn = bx * 256;
    const int lane = t & 63, wv = t >> 6;
    const int wm = wv >> 2, wn = wv & 3;
    const int kb = lane >> 4, lr16 = lane & 15;
    const int NT = K >> 6;

    f32x4 acc[4][4];
#pragma unroll
    for (int i = 0; i < 4; ++i)
#pragma unroll
        for (int j = 0; j < 4; ++j) acc[i][j] = (f32x4)0.0f;

    const int arow = t >> 2;
    const int ac2 = (t & 3) ^ ((arow >> 1) & 3);
    const f16* Abase = A + (size_t)(bm + arow) * lda + ac2 * 8;
    const char* Bbase = fmt + (size_t)bn * 64 + (size_t)t * 16;
    const size_t BKstep = (size_t)N * 64;
    char* ldsT = ldsb + t * 16;

    auto STAGE_A = [&](int p, int kh, int kt) {
        GLDS16(Abase + kt * 64 + kh * 32, ldsT + p * 32768 + kh * 16384);
    };
    auto STAGE_B = [&](int p, int kh, int kt) {
        GLDS16(Bbase + (size_t)(kt * 2 + kh) * BKstep, ldsT + 65536 + p * 32768 + kh * 16384);
    };

    f16x8 af[4], bf[4];

    const int T1 = NT > 1 ? 1 : 0;
    STAGE_B(0, 0, 0); STAGE_A(0, 0, 0);
    STAGE_B(0, 1, 0); STAGE_A(0, 1, 0);
    STAGE_B(1, 0, T1); STAGE_A(1, 0, T1);
    asm volatile("s_waitcnt vmcnt(4)" ::: "memory");
    __builtin_amdgcn_s_barrier();
    __builtin_amdgcn_sched_barrier(0);

    const int NI = NT >> 1;
    for (int i = 0; i < NI; ++i) {
        const int tA = 2 * i + 1 < NT ? 2 * i + 1 : NT - 1;
        const int tB = 2 * i + 2 < NT ? 2 * i + 2 : NT - 1;
        const int tC = 2 * i + 3 < NT ? 2 * i + 3 : NT - 1;
        PH(0, 0, 0, STAGE_B(1, 1, tA))
        PH(0, 0, 1, STAGE_A(1, 1, tA))
        PH(0, 1, 0, STAGE_B(0, 0, tB))
        PH(0, 1, 1, STAGE_A(0, 0, tB))
        PH(1, 0, 0, STAGE_B(0, 1, tB))
        PH(1, 0, 1, STAGE_A(0, 1, tB))
        PH(1, 1, 0, STAGE_B(1, 0, tC))
        PH(1, 1, 1, STAGE_A(1, 0, tC))
    }
    asm volatile("s_waitcnt vmcnt(0)" ::: "memory");

    if (EPI == 3) {
        // ---- fused conv epilogue: acc tile -> LDS (up/gate split, CSWZ layout)
        __syncthreads();                    // all loop-phase LDS reads retired
        f16* upT = (f16*)ldsb;              // [256][128] via CSWZ
        f16* gtT = (f16*)(ldsb + 65536);
#pragma unroll
        for (int fm = 0; fm < 4; ++fm) {
            const int row = wm * 64 + fm * 16 + kb * 4;
#pragma unroll
            for (int fn = 0; fn < 4; ++fn) {
                const int col = wn * 64 + fn * 16 + lr16;
                f16* dst = (col & 1) ? gtT : upT;
                const int c = col >> 1;
#pragma unroll
                for (int r = 0; r < 4; ++r)
                    dst[CSWZ(row + r, c)] = (f16)acc[fm][fn][r];
            }
        }
        __syncthreads();
        const int c = t & 127, rg = t >> 7;       // col, row-group (8 x 32 rows)
        const int cg = bx * 128 + c;              // global conv channel
        const float4 tp = *(const float4*)(cw + (size_t)cg * 4);
        const float bias = cb[cg];
        const int r0 = rg * 32;
        float w0 = 0.f, w1 = 0.f, w2 = 0.f;       // zeros correct iff seq-start band
        if (r0 > 0) {
            w0 = (float)upT[CSWZ(r0 - 3, c)];
            w1 = (float)upT[CSWZ(r0 - 2, c)];
            w2 = (float)upT[CSWZ(r0 - 1, c)];
        }
        f16* vout = (f16*)Cv;
#pragma unroll 8
        for (int i = 0; i < 32; ++i) {
            const int r = r0 + i;
            const float u = (float)upT[CSWZ(r, c)];
            const float g = (float)gtT[CSWZ(r, c)];
            float a = bias;
            a = fmaf(w0, tp.x, a); a = fmaf(w1, tp.y, a);
            a = fmaf(w2, tp.z, a); a = fmaf(u, tp.w, a);
            vout[(size_t)(bm + r) * 2048 + cg] = (f16)(silu_f(g) * silu_f(a));
            w0 = w1; w1 = w2; w2 = u;
        }
        const int band = bm >> 8;
        if (rg == 0) {                            // boundary dumps for fixup
#pragma unroll
            for (int i = 0; i < 3; ++i) {
                tailb[((size_t)band * 9 + i) * 2048 + cg]     = upT[CSWZ(i, c)];
                tailb[((size_t)band * 9 + 6 + i) * 2048 + cg] = gtT[CSWZ(i, c)];
            }
        } else if (rg == 7) {
#pragma unroll
            for (int i = 0; i < 3; ++i)
                tailb[((size_t)band * 9 + 3 + i) * 2048 + cg] = upT[CSWZ(253 + i, c)];
        }
        return;
    }

#pragma unroll
    for (int fm = 0; fm < 4; ++fm) {
        const int row0 = bm + wm * 64 + fm * 16 + kb * 4;
#pragma unroll
        for (int fn = 0; fn < 4; ++fn) {
            const int col = bn + wn * 64 + fn * 16 + lr16;
#pragma unroll
            for (int r = 0; r < 4; ++r) {
                float o = acc[fm][fn][r];
                if (EPI == 1) {
                    if (col < DM) o = phi_f(o) * 0.125f;
                    else if (col < 2 * DM) o = phi_f(o);
                }
                if (EPI == 2) {
                    ((float*)Cv)[(size_t)(row0 + r) * N + col] =
                        o + addx[(size_t)(row0 + r) * N + col];
                } else {
                    ((f16*)Cv)[(size_t)(row0 + r) * N + col] = (f16)o;
                }
            }
        }
    }
}

// ---------------- 3. conv boundary fixup: rows 0..2 of non-seq-start bands ------
__global__ __launch_bounds__(256) void fixconv_k(const f16* __restrict__ tailb,
                                                 f16* __restrict__ val,
                                                 const float* __restrict__ cw,
                                                 const float* __restrict__ cb)
{
    const int b = blockIdx.x;
    if ((b & 15) == 0) return;                    // sequence-start band: already exact
    const int c0 = threadIdx.x * 8;
    float um[3][8], u[3][8], g[3][8];
#pragma unroll
    for (int i = 0; i < 3; ++i) {
        const f16x8 a  = *(const f16x8*)(tailb + ((size_t)(b - 1) * 9 + 3 + i) * 2048 + c0);
        const f16x8 bb = *(const f16x8*)(tailb + ((size_t)b * 9 + i) * 2048 + c0);
        const f16x8 gg = *(const f16x8*)(tailb + ((size_t)b * 9 + 6 + i) * 2048 + c0);
#pragma unroll
        for (int j = 0; j < 8; ++j) {
            um[i][j] = (float)a[j]; u[i][j] = (float)bb[j]; g[i][j] = (float)gg[j];
        }
    }
#pragma unroll
    for (int r = 0; r < 3; ++r) {
        f16x8 o;
#pragma unroll
        for (int j = 0; j < 8; ++j) {
            const int cg = c0 + j;
            const float4 tp = *(const float4*)(cw + (size_t)cg * 4);
            float a = cb[cg];
            const float wnd[6] = {um[0][j], um[1][j], um[2][j], u[0][j], u[1][j], u[2][j]};
            a = fmaf(wnd[r],     tp.x, a);
            a = fmaf(wnd[r + 1], tp.y, a);
            a = fmaf(wnd[r + 2], tp.z, a);
            a = fmaf(wnd[r + 3], tp.w, a);
            o[j] = (f16)(silu_f(g[r][j]) * silu_f(a));
        }
        *(f16x8*)(val + ((size_t)b * 256 + r) * 2048 + c0) = o;
    }
}

// ---------------- 4a. per-chunk outer products: GT[b][h][ch][e][d] = (K^T V)^T --
__global__ __launch_bounds__(256) void gscan_g_k(const f16* __restrict__ qkv,
                                                 f16* __restrict__ GT)
{
    __shared__ float Ks[4096];
    __shared__ float Vs[4096];
    const int t = threadIdx.x, ch = blockIdx.x, h = blockIdx.y, b = blockIdx.z;
    const int r = t >> 2, c16 = (t & 3) * 16;
    const f16* kp = qkv + ((size_t)b * SEQL + ch * 64 + r) * 3072 + DM + h * 64 + c16;
#pragma unroll
    for (int i = 0; i < 2; ++i) {
        const f16x8 kv = *(const f16x8*)(kp + 8 * i);
        const f16x8 vv = *(const f16x8*)(kp + DM + 8 * i);
#pragma unroll
        for (int j = 0; j < 8; ++j) {
            Ks[r * 64 + c16 + 8 * i + j] = (float)kv[j];
            Vs[r * 64 + c16 + 8 * i + j] = (float)vv[j];
        }
    }
    __syncthreads();
    const int e4 = (t >> 4) * 4, d4 = (t & 15) * 4;
    float4 ag[4] = {};
#pragma unroll 4
    for (int c = 0; c < 64; ++c) {
        float va[4];
        *(float4*)va = *(const float4*)(Vs + c * 64 + e4);
        const float4 ka = *(const float4*)(Ks + c * 64 + d4);
        ag[0].x = fmaf(va[0], ka.x, ag[0].x); ag[0].y = fmaf(va[0], ka.y, ag[0].y);
        ag[0].z = fmaf(va[0], ka.z, ag[0].z); ag[0].w = fmaf(va[0], ka.w, ag[0].w);
        ag[1].x = fmaf(va[1], ka.x, ag[1].x); ag[1].y = fmaf(va[1], ka.y, ag[1].y);
        ag[1].z = fmaf(va[1], ka.z, ag[1].z); ag[1].w = fmaf(va[1], ka.w, ag[1].w);
        ag[2].x = fmaf(va[2], ka.x, ag[2].x); ag[2].y = fmaf(va[2], ka.y, ag[2].y);
        ag[2].z = fmaf(va[2], ka.z, ag[2].z); ag[2].w = fmaf(va[2], ka.w, ag[2].w);
        ag[3].x = fmaf(va[3], ka.x, ag[3].x); ag[3].y = fmaf(va[3], ka.y, ag[3].y);
        ag[3].z = fmaf(va[3], ka.z, ag[3].z); ag[3].w = fmaf(va[3], ka.w, ag[3].w);
    }
    f16* go = GT + (((size_t)b * 16 + h) * 64 + ch) * 4096 + e4 * 64 + d4;
#pragma unroll
    for (int i = 0; i < 4; ++i) {
        f16x4 o;
        o[0] = (f16)ag[i].x; o[1] = (f16)ag[i].y;
        o[2] = (f16)ag[i].z; o[3] = (f16)ag[i].w;
        *(f16x4*)(go + i * 64) = o;
    }
}

// ---------------- 4b. in-place exclusive prefix over chunks (f16x2, fp32 carry) -
__global__ __launch_bounds__(256) void gprefix_k(f16* __restrict__ G)
{
    const int bh = blockIdx.x >> 3, sl = blockIdx.x & 7;
    f16x2* p = (f16x2*)(G + (size_t)bh * 64 * 4096) + sl * 256 + threadIdx.x;
    float r0 = 0.0f, r1 = 0.0f;
#pragma unroll 4
    for (int ch = 0; ch < 64; ++ch) {
        const f16x2 g = *p;
        f16x2 o; o[0] = (f16)r0; o[1] = (f16)r1;
        *p = o;
        r0 += (float)g[0]; r1 += (float)g[1];
        p += 2048;
    }
}

// ---------------- 4c. per-chunk read via MFMA: y = q*M_excl + tril(q k^T) v -----
__global__ __launch_bounds__(256) void gscan_y_k(const f16* __restrict__ qkv,
                                                 const f16* __restrict__ GT,
                                                 f16* __restrict__ y)
{
    __shared__ __align__(16) char lds[40960];
    f16* Qs = (f16*)lds;
    f16* Ks = (f16*)(lds + 8192);
    f16* Ms = (f16*)(lds + 16384);
    f16* Vt = (f16*)(lds + 24576);
    f16* Ss = (f16*)(lds + 32768);

    const int t = threadIdx.x, ch = blockIdx.x, h = blockIdx.y, b = blockIdx.z;
    const int lane = t & 63, w = t >> 6;
    const int kb = lane >> 4, lr16 = lane & 15;

    const int r = t >> 2;
    const int c0 = (t & 3) * 2;
    const int rkey = (r >> 1) & 3;
    const f16* qp = qkv + ((size_t)b * SEQL + ch * 64 + r) * 3072 + h * 64;
    const f16* mp = GT + (((size_t)b * 16 + h) * 64 + ch) * 4096 + r * 64;
#pragma unroll
    for (int cc = 0; cc < 2; ++cc) {
        const int c = c0 + cc;
        const int sw = c ^ rkey;
        const f16x8 qv = *(const f16x8*)(qp + c * 8);
        const f16x8 kv = *(const f16x8*)(qp + DM + c * 8);
        const f16x8 vv = *(const f16x8*)(qp + 2 * DM + c * 8);
        const f16x8 mv = *(const f16x8*)(mp + c * 8);
        *(f16x8*)(Qs + r * 64 + sw * 8) = qv;
        *(f16x8*)(Ks + r * 64 + sw * 8) = kv;
        *(f16x8*)(Ms + r * 64 + sw * 8) = mv;
#pragma unroll
        for (int jj = 0; jj < 8; ++jj) {
            const int j = c * 8 + jj;
            Vt[j * 64 + ((((r >> 3) ^ ((j >> 1) & 3)) << 3) + (r & 7))] = vv[jj];
        }
    }
    __syncthreads();

    f16x8 af[2];
    {
        const int row = w * 16 + lr16;
        const int sz = (row >> 1) & 3;
        af[0] = *(const f16x8*)(Qs + row * 64 + (kb ^ sz) * 8);
        af[1] = *(const f16x8*)(Qs + row * 64 + (4 + (kb ^ sz)) * 8);
    }
    f32x4 accs[4];
#pragma unroll
    for (int te = 0; te < 4; ++te) accs[te] = (f32x4)0.0f;
#pragma unroll
    for (int te = 0; te < 4; ++te) {
        const int er = te * 16 + lr16;
        const int es = (er >> 1) & 3;
        const f16x8 b0 = *(const f16x8*)(Ks + er * 64 + (kb ^ es) * 8);
        const f16x8 b1 = *(const f16x8*)(Ks + er * 64 + (4 + (kb ^ es)) * 8);
        accs[te] = __builtin_amdgcn_mfma_f32_16x16x32_f16(af[0], b0, accs[te], 0, 0, 0);
        accs[te] = __builtin_amdgcn_mfma_f32_16x16x32_f16(af[1], b1, accs[te], 0, 0, 0);
    }
#pragma unroll
    for (int te = 0; te < 4; ++te)
#pragma unroll
        for (int rr = 0; rr < 4; ++rr) {
            const int rc = w * 16 + kb * 4 + rr;
            const int ce = te * 16 + lr16;
            const float v = (ce <= rc) ? accs[te][rr] : 0.0f;
            Ss[rc * 64 + ((((ce >> 3) ^ ((rc >> 1) & 3)) << 3) + (ce & 7))] = (f16)v;
        }
    __syncthreads();

    f16x8 as2[2];
    {
        const int row = w * 16 + lr16;
        const int sz = (row >> 1) & 3;
        as2[0] = *(const f16x8*)(Ss + row * 64 + (kb ^ sz) * 8);
        as2[1] = *(const f16x8*)(Ss + row * 64 + (4 + (kb ^ sz)) * 8);
    }
    f32x4 accy[4];
#pragma unroll
    for (int tj = 0; tj < 4; ++tj) accy[tj] = (f32x4)0.0f;
#pragma unroll
    for (int tj = 0; tj < 4; ++tj) {
        const int jr = tj * 16 + lr16;
        const int js = (jr >> 1) & 3;
        const f16x8 m0 = *(const f16x8*)(Ms + jr * 64 + (kb ^ js) * 8);
        const f16x8 m1 = *(const f16x8*)(Ms + jr * 64 + (4 + (kb ^ js)) * 8);
        const f16x8 v0 = *(const f16x8*)(Vt + jr * 64 + (kb ^ js) * 8);
        const f16x8 v1 = *(const f16x8*)(Vt + jr * 64 + (4 + (kb ^ js)) * 8);
        accy[tj] = __builtin_amdgcn_mfma_f32_16x16x32_f16(af[0],  m0, accy[tj], 0, 0, 0);
        accy[tj] = __builtin_amdgcn_mfma_f32_16x16x32_f16(af[1],  m1, accy[tj], 0, 0, 0);
        accy[tj] = __builtin_amdgcn_mfma_f32_16x16x32_f16(as2[0], v0, accy[tj], 0, 0, 0);
        accy[tj] = __builtin_amdgcn_mfma_f32_16x16x32_f16(as2[1], v1, accy[tj], 0, 0, 0);
    }
    f16* yo = y + ((size_t)b * SEQL + ch * 64) * DM + h * 64;
#pragma unroll
    for (int tj = 0; tj < 4; ++tj)
#pragma unroll
        for (int rr = 0; rr < 4; ++rr) {
            const int rc = w * 16 + kb * 4 + rr;
            yo[(size_t)rc * DM + tj * 16 + lr16] = (f16)accy[tj][rr];
        }
}

// ---------------- launch --------------------------------------------------------
extern "C" void kernel_launch(void* const* d_in, const int* in_sizes, int n_in,
                              void* d_out, int out_size, void* d_ws, size_t ws_size,
                              hipStream_t stream)
{
    const float* x      = (const float*)d_in[0];
    const float* norm_w = (const float*)d_in[1];
    const float* w_up   = (const float*)d_in[2];
    const float* w_gate = (const float*)d_in[3];
    const float* w_down = (const float*)d_in[4];
    const float* conv_w = (const float*)d_in[5];
    const float* conv_b = (const float*)d_in[6];
    const float* wq     = (const float*)d_in[7];
    const float* wk     = (const float*)d_in[8];
    const float* wv     = (const float*)d_in[9];
    const float* wo     = (const float*)d_in[10];
    float* out = (float*)d_out;

    const size_t BIG_NEED = 247463936ull;
    const bool big = ws_size >= BIG_NEED;

    if (big) {
        // layout (246.3 MB): val 64 | qkv 96 | hb 32 | fmtD 4 | fmtQKV 6 | fmtO 2 |
        //                    tail 2.25 | xn 32 | fmtUG 8 ; G (33.5) overlays xn+fmtUG
        char* p = (char*)d_ws;
        f16* val = (f16*)p;               p += (size_t)NRALL * 2048 * 2;
        f16* qkvb = (f16*)p;              p += (size_t)NRALL * 3072 * 2;
        f16* hb  = (f16*)p;               p += (size_t)NRALL * DM * 2;
        char* fmtD   = p;                 p += (size_t)64 * 1024 * 64;
        char* fmtQKV = p;                 p += (size_t)32 * 3072 * 64;
        char* fmtO   = p;                 p += (size_t)32 * 1024 * 64;
        f16* tailb = (f16*)p;             p += (size_t)64 * 9 * 2048 * 2;
        f16* xn = (f16*)p;                p += (size_t)NRALL * DM * 2;
        char* fmtUG  = p;
        f16* G = (f16*)xn;
        f16* yb = hb;

        prep_k<<<NRALL + 640, 256, 0, stream>>>(x, norm_w, xn, w_up, w_gate, w_down,
                                                wq, wk, wv, wo, fmtUG, fmtD, fmtQKV, fmtO);

        mg256_k<3><<<16 * 64, 1024, 0, stream>>>(xn, DM, fmtUG, val, 4096, DM, 16, nullptr,
                                                 conv_w, conv_b, tailb);
        fixconv_k<<<64, 256, 0, stream>>>(tailb, val, conv_w, conv_b);
        mg256_k<0><<<4 * 64, 1024, 0, stream>>>(val, 2048, fmtD, hb, 1024, DI, 4, nullptr);
        mg256_k<1><<<12 * 64, 1024, 0, stream>>>(hb, DM, fmtQKV, qkvb, 3072, DM, 12, nullptr);

        gscan_g_k<<<dim3(64, 16, 4), 256, 0, stream>>>(qkvb, G);
        gprefix_k<<<512, 256, 0, stream>>>(G);
        gscan_y_k<<<dim3(64, 16, 4), 256, 0, stream>>>(qkvb, G, yb);

        mg256_k<2><<<4 * 64, 1024, 0, stream>>>(yb, DM, fmtO, out, 1024, DM, 4, x);
    } else {
        // compact per-batch path (~109 MB)
        char* p = (char*)d_ws;
        f16* xn = (f16*)p;                p += (size_t)NRALL * DM * 2;
        f16* val = (f16*)p;               p += (size_t)SEQL * 2048 * 2;
        f16* qkvb = (f16*)p;              p += (size_t)SEQL * 3072 * 2;
        f16* hb  = (f16*)p;               p += (size_t)SEQL * DM * 2;
        f16* G = (f16*)p;                 p += (size_t)16 * 64 * 4096 * 2;
        char* fmtUG  = p;                 p += (size_t)32 * 4096 * 64;
        char* fmtD   = p;                 p += (size_t)64 * 1024 * 64;
        char* fmtQKV = p;                 p += (size_t)32 * 3072 * 64;
        char* fmtO   = p;                 p += (size_t)32 * 1024 * 64;
        f16* tailb = (f16*)p;
        f16* yb = hb;

        prep_k<<<NRALL + 640, 256, 0, stream>>>(x, norm_w, xn, w_up, w_gate, w_down,
                                                wq, wk, wv, wo, fmtUG, fmtD, fmtQKV, fmtO);

        for (int b = 0; b < 4; ++b) {
            const f16* xnb = xn + (size_t)b * SEQL * DM;
            mg256_k<3><<<16 * 16, 1024, 0, stream>>>(xnb, DM, fmtUG, val, 4096, DM, 16, nullptr,
                                                     conv_w, conv_b, tailb);
            fixconv_k<<<16, 256, 0, stream>>>(tailb, val, conv_w, conv_b);
            mg256_k<0><<<4 * 16, 1024, 0, stream>>>(val, 2048, fmtD, hb, 1024, DI, 4, nullptr);
            mg256_k<1><<<12 * 16, 1024, 0, stream>>>(hb, DM, fmtQKV, qkvb, 3072, DM, 12, nullptr);
            gscan_g_k<<<dim3(64, 16, 1), 256, 0, stream>>>(qkvb, G);
            gprefix_k<<<128, 256, 0, stream>>>(G);
            gscan_y_k<<<dim3(64, 16, 1), 256, 0, stream>>>(qkvb, G, yb);
            mg256_k<2><<<4 * 16, 1024, 0, stream>>>(yb, DM, fmtO,
                                                    out + (size_t)b * SEQL * DM, 1024, DM, 4,
                                                    x + (size_t)b * SEQL * DM);
        }
    }
}

// Round 18
// 516.741 us; speedup vs baseline: 6.8168x; 1.0033x over previous
//
#include <hip/hip_runtime.h>
#include <hip/hip_fp16.h>
#include <cstdint>

// Problem constants (B=4, S=4096, D=1024)
#define NRALL 16384
#define DM    1024
#define DI    2048
#define SEQL  4096

typedef _Float16 f16;
typedef _Float16 f16x8 __attribute__((ext_vector_type(8)));
typedef _Float16 f16x4 __attribute__((ext_vector_type(4)));
typedef _Float16 f16x2 __attribute__((ext_vector_type(2)));
typedef float    f32x4 __attribute__((ext_vector_type(4)));

__device__ __forceinline__ float phi_f(float t)  { return t > 0.0f ? t + 1.0f : __expf(t); }
__device__ __forceinline__ float silu_f(float t) { return t / (1.0f + __expf(-t)); }

#define GLDS16(g, l)                                                            \
    __builtin_amdgcn_global_load_lds(                                           \
        (const __attribute__((address_space(1))) void*)(g),                     \
        (__attribute__((address_space(3))) void*)(l), 16, 0, 0)

// epilogue tile index: XOR column with row-derived key -> kb groups hit disjoint
// bank sets. Key is a multiple of 8 -> even col pairs stay adjacent (f16x2-safe).
#define CSWZ(row, c) ((row) * 128 + ((c) ^ ((((row) >> 2) & 7) << 3)))

// ---------------- 1. merged prep: rmsnorm rows + weight format ------------------
// ng = n*mul + off : UG uses mul=2 (up even cols, gate odd) so the GEMM tile has
// up[c] and gate[c] together for the fused conv epilogue.
__device__ __forceinline__ void wfmt_one(const float* __restrict__ W, char* __restrict__ fmt,
                                         int n, int kt, int Nw, int Ntot, int mul, int off)
{
    const int ng = n * mul + off;
#pragma unroll
    for (int kh = 0; kh < 2; ++kh) {
        char* o = fmt + ((size_t)(kt * 2 + kh) * Ntot + ng) * 64;
#pragma unroll
        for (int c2 = 0; c2 < 4; ++c2) {
            f16x8 p;
#pragma unroll
            for (int j = 0; j < 8; ++j)
                p[j] = (f16)W[(size_t)(kt * 64 + kh * 32 + c2 * 8 + j) * Nw + n];
            *(f16x8*)(o + ((c2 ^ ((ng >> 1) & 3)) << 4)) = p;
        }
    }
}

__global__ __launch_bounds__(256) void prep_k(const float* __restrict__ x,
                                              const float* __restrict__ nw,
                                              f16* __restrict__ xn,
                                              const float* __restrict__ w_up,
                                              const float* __restrict__ w_gate,
                                              const float* __restrict__ w_down,
                                              const float* __restrict__ wq,
                                              const float* __restrict__ wk,
                                              const float* __restrict__ wv,
                                              const float* __restrict__ wo,
                                              char* __restrict__ fmtUG,
                                              char* __restrict__ fmtD,
                                              char* __restrict__ fmtQKV,
                                              char* __restrict__ fmtO)
{
    const int t = threadIdx.x;
    if (blockIdx.x < NRALL) {
        const int r = blockIdx.x;
        const float4 v = *(const float4*)(x + (size_t)r * DM + t * 4);
        float s = v.x * v.x + v.y * v.y + v.z * v.z + v.w * v.w;
#pragma unroll
        for (int m = 1; m < 64; m <<= 1) s += __shfl_xor(s, m);
        __shared__ float ws4[4];
        if ((t & 63) == 0) ws4[t >> 6] = s;
        __syncthreads();
        const float tot = ws4[0] + ws4[1] + ws4[2] + ws4[3];
        const float sc = rsqrtf(tot * (1.0f / DM) + 1e-5f);
        const float4 w = *(const float4*)(nw + t * 4);
        f16x4 o;
        o[0] = (f16)(v.x * sc * w.x); o[1] = (f16)(v.y * sc * w.y);
        o[2] = (f16)(v.z * sc * w.z); o[3] = (f16)(v.w * sc * w.w);
        *(f16x4*)(xn + (size_t)r * DM + t * 4) = o;
        return;
    }
    int id = blockIdx.x - NRALL;
    if (id < 128) { wfmt_one(w_up,   fmtUG,  (id % 8) * 256 + t, id / 8, DI, 4096, 2, 0); return; }
    id -= 128;
    if (id < 128) { wfmt_one(w_gate, fmtUG,  (id % 8) * 256 + t, id / 8, DI, 4096, 2, 1); return; }
    id -= 128;
    if (id < 128) { wfmt_one(w_down, fmtD,   (id % 4) * 256 + t, id / 4, DM, 1024, 1, 0); return; }
    id -= 128;
    if (id < 64)  { wfmt_one(wq,     fmtQKV, (id % 4) * 256 + t, id / 4, DM, 3072, 1, 0);    return; }
    id -= 64;
    if (id < 64)  { wfmt_one(wk,     fmtQKV, (id % 4) * 256 + t, id / 4, DM, 3072, 1, 1024); return; }
    id -= 64;
    if (id < 64)  { wfmt_one(wv,     fmtQKV, (id % 4) * 256 + t, id / 4, DM, 3072, 1, 2048); return; }
    id -= 64;
    wfmt_one(wo, fmtO, (id % 4) * 256 + t, id / 4, DM, 1024, 1, 0);
}

// ---------------- 2. 256x256 MFMA GEMM, 16 waves (4m x 4n), 8-phase -------------
// EPI: 0 f16 out; 1 qkv epilogue (phi ranges); 2 +addx fp32 out;
//      3 fused conv+silu+gate (UG interleaved tile -> val[.][2048]) + boundary dumps.
#define PH(p, ks, mh, STAGE_STMT)                                                 \
    {                                                                             \
        if ((mh) == 0) {                                                          \
            _Pragma("unroll")                                                     \
            for (int q = 0; q < 2; ++q) {                                         \
                const int row = wm * 64 + q * 16 + lr16;                          \
                af[q] = *(const f16x8*)(ldsb + (p) * 32768 + (ks) * 16384         \
                        + row * 64 + ((kb ^ ((row >> 1) & 3)) << 4));             \
            }                                                                     \
            _Pragma("unroll")                                                     \
            for (int q = 0; q < 4; ++q) {                                         \
                const int n = wn * 64 + q * 16 + lr16;                            \
                bf[q] = *(const f16x8*)(ldsb + 65536 + (p) * 32768 + (ks) * 16384 \
                        + n * 64 + ((kb ^ ((n >> 1) & 3)) << 4));                 \
            }                                                                     \
        } else {                                                                  \
            _Pragma("unroll")                                                     \
            for (int q = 0; q < 2; ++q) {                                         \
                const int row = wm * 64 + (q + 2) * 16 + lr16;                    \
                af[2 + q] = *(const f16x8*)(ldsb + (p) * 32768 + (ks) * 16384     \
                            + row * 64 + ((kb ^ ((row >> 1) & 3)) << 4));         \
            }                                                                     \
        }                                                                         \
        STAGE_STMT;                                                               \
        asm volatile("s_waitcnt vmcnt(3)" ::: "memory");                          \
        __builtin_amdgcn_sched_barrier(0);                                        \
        __builtin_amdgcn_s_barrier();                                             \
        asm volatile("s_waitcnt lgkmcnt(0)" ::: "memory");                        \
        __builtin_amdgcn_sched_barrier(0);                                        \
        __builtin_amdgcn_s_setprio(1);                                            \
        _Pragma("unroll")                                                         \
        for (int q = 0; q < 2; ++q) {                                             \
            acc[(mh) * 2 + q][0] = __builtin_amdgcn_mfma_f32_16x16x32_f16(        \
                af[(mh) * 2 + q], bf[0], acc[(mh) * 2 + q][0], 0, 0, 0);          \
            acc[(mh) * 2 + q][1] = __builtin_amdgcn_mfma_f32_16x16x32_f16(        \
                af[(mh) * 2 + q], bf[1], acc[(mh) * 2 + q][1], 0, 0, 0);          \
            acc[(mh) * 2 + q][2] = __builtin_amdgcn_mfma_f32_16x16x32_f16(        \
                af[(mh) * 2 + q], bf[2], acc[(mh) * 2 + q][2], 0, 0, 0);          \
            acc[(mh) * 2 + q][3] = __builtin_amdgcn_mfma_f32_16x16x32_f16(        \
                af[(mh) * 2 + q], bf[3], acc[(mh) * 2 + q][3], 0, 0, 0);          \
        }                                                                         \
        __builtin_amdgcn_s_setprio(0);                                            \
        __builtin_amdgcn_sched_barrier(0);                                        \
    }

template <int EPI>
__global__ __launch_bounds__(1024) void mg256_k(const f16* __restrict__ A, int lda,
                                                const char* __restrict__ fmt,
                                                void* __restrict__ Cv,
                                                int N, int K, int gx,
                                                const float* __restrict__ addx,
                                                const float* __restrict__ cw = nullptr,
                                                const float* __restrict__ cb = nullptr,
                                                f16* __restrict__ tailb = nullptr)
{
    __shared__ __align__(16) char ldsb[131072];

    const int t = threadIdx.x;
    int wid = blockIdx.x;
    { const int cpx = gridDim.x >> 3; wid = (wid & 7) * cpx + (wid >> 3); }  // XCD swizzle
    const int bx = wid % gx, by = wid / gx;
    const int bm = by * 256, bn = bx * 256;
    const int lane = t & 63, wv = t >> 6;
    const int wm = wv >> 2, wn = wv & 3;
    const int kb = lane >> 4, lr16 = lane & 15;
    const int NT = K >> 6;

    f32x4 acc[4][4];
#pragma unroll
    for (int i = 0; i < 4; ++i)
#pragma unroll
        for (int j = 0; j < 4; ++j) acc[i][j] = (f32x4)0.0f;

    const int arow = t >> 2;
    const int ac2 = (t & 3) ^ ((arow >> 1) & 3);
    const f16* Abase = A + (size_t)(bm + arow) * lda + ac2 * 8;
    const char* Bbase = fmt + (size_t)bn * 64 + (size_t)t * 16;
    const size_t BKstep = (size_t)N * 64;
    char* ldsT = ldsb + t * 16;

    auto STAGE_A = [&](int p, int kh, int kt) {
        GLDS16(Abase + kt * 64 + kh * 32, ldsT + p * 32768 + kh * 16384);
    };
    auto STAGE_B = [&](int p, int kh, int kt) {
        GLDS16(Bbase + (size_t)(kt * 2 + kh) * BKstep, ldsT + 65536 + p * 32768 + kh * 16384);
    };

    f16x8 af[4], bf[4];

    const int T1 = NT > 1 ? 1 : 0;
    STAGE_B(0, 0, 0); STAGE_A(0, 0, 0);
    STAGE_B(0, 1, 0); STAGE_A(0, 1, 0);
    STAGE_B(1, 0, T1); STAGE_A(1, 0, T1);
    asm volatile("s_waitcnt vmcnt(4)" ::: "memory");
    __builtin_amdgcn_s_barrier();
    __builtin_amdgcn_sched_barrier(0);

    const int NI = NT >> 1;
    for (int i = 0; i < NI; ++i) {
        const int tA = 2 * i + 1 < NT ? 2 * i + 1 : NT - 1;
        const int tB = 2 * i + 2 < NT ? 2 * i + 2 : NT - 1;
        const int tC = 2 * i + 3 < NT ? 2 * i + 3 : NT - 1;
        PH(0, 0, 0, STAGE_B(1, 1, tA))
        PH(0, 0, 1, STAGE_A(1, 1, tA))
        PH(0, 1, 0, STAGE_B(0, 0, tB))
        PH(0, 1, 1, STAGE_A(0, 0, tB))
        PH(1, 0, 0, STAGE_B(0, 1, tB))
        PH(1, 0, 1, STAGE_A(0, 1, tB))
        PH(1, 1, 0, STAGE_B(1, 0, tC))
        PH(1, 1, 1, STAGE_A(1, 0, tC))
    }
    asm volatile("s_waitcnt vmcnt(0)" ::: "memory");

    if (EPI == 3) {
        // ---- fused conv epilogue: acc tile -> LDS (up/gate split, CSWZ layout)
        __syncthreads();                    // all loop-phase LDS reads retired
        f16* upT = (f16*)ldsb;              // [256][128] via CSWZ
        f16* gtT = (f16*)(ldsb + 65536);
#pragma unroll
        for (int fm = 0; fm < 4; ++fm) {
            const int row = wm * 64 + fm * 16 + kb * 4;
#pragma unroll
            for (int fn = 0; fn < 4; ++fn) {
                const int col = wn * 64 + fn * 16 + lr16;
                f16* dst = (col & 1) ? gtT : upT;
                const int c = col >> 1;
#pragma unroll
                for (int r = 0; r < 4; ++r)
                    dst[CSWZ(row + r, c)] = (f16)acc[fm][fn][r];
            }
        }
        __syncthreads();
        // thread -> col-pair pi (2 channels), 16-row group rg: all LDS accesses dword
        const int pi = t & 63, rg = t >> 6;
        const int c2 = pi * 2;
        const int cg = bx * 128 + c2;
        const float4 tpa = *(const float4*)(cw + (size_t)cg * 4);
        const float4 tpb = *(const float4*)(cw + (size_t)(cg + 1) * 4);
        const float2 bias = *(const float2*)(cb + cg);
        const int r0 = rg * 16;
        float wa0 = 0.f, wa1 = 0.f, wa2 = 0.f, wb0 = 0.f, wb1 = 0.f, wb2 = 0.f;
        if (r0 > 0) {
            const f16x2 x0 = *(const f16x2*)(upT + CSWZ(r0 - 3, c2));
            const f16x2 x1 = *(const f16x2*)(upT + CSWZ(r0 - 2, c2));
            const f16x2 x2 = *(const f16x2*)(upT + CSWZ(r0 - 1, c2));
            wa0 = (float)x0[0]; wb0 = (float)x0[1];
            wa1 = (float)x1[0]; wb1 = (float)x1[1];
            wa2 = (float)x2[0]; wb2 = (float)x2[1];
        }
        f16* vout = (f16*)Cv;
#pragma unroll 4
        for (int i = 0; i < 16; ++i) {
            const int r = r0 + i;
            const f16x2 u2 = *(const f16x2*)(upT + CSWZ(r, c2));
            const f16x2 g2 = *(const f16x2*)(gtT + CSWZ(r, c2));
            const float ua = (float)u2[0], ub = (float)u2[1];
            float aa = bias.x, ab = bias.y;
            aa = fmaf(wa0, tpa.x, aa); aa = fmaf(wa1, tpa.y, aa);
            aa = fmaf(wa2, tpa.z, aa); aa = fmaf(ua,  tpa.w, aa);
            ab = fmaf(wb0, tpb.x, ab); ab = fmaf(wb1, tpb.y, ab);
            ab = fmaf(wb2, tpb.z, ab); ab = fmaf(ub,  tpb.w, ab);
            f16x2 o2;
            o2[0] = (f16)(silu_f((float)g2[0]) * silu_f(aa));
            o2[1] = (f16)(silu_f((float)g2[1]) * silu_f(ab));
            *(f16x2*)(vout + (size_t)(bm + r) * 2048 + cg) = o2;
            wa0 = wa1; wa1 = wa2; wa2 = ua;
            wb0 = wb1; wb1 = wb2; wb2 = ub;
        }
        const int band = bm >> 8;
        if (rg == 0) {                            // boundary dumps for fixup
#pragma unroll
            for (int i = 0; i < 3; ++i) {
                *(f16x2*)(tailb + ((size_t)band * 9 + i) * 2048 + cg) =
                    *(const f16x2*)(upT + CSWZ(i, c2));
                *(f16x2*)(tailb + ((size_t)band * 9 + 6 + i) * 2048 + cg) =
                    *(const f16x2*)(gtT + CSWZ(i, c2));
            }
        } else if (rg == 15) {
#pragma unroll
            for (int i = 0; i < 3; ++i)
                *(f16x2*)(tailb + ((size_t)band * 9 + 3 + i) * 2048 + cg) =
                    *(const f16x2*)(upT + CSWZ(253 + i, c2));
        }
        return;
    }

#pragma unroll
    for (int fm = 0; fm < 4; ++fm) {
        const int row0 = bm + wm * 64 + fm * 16 + kb * 4;
#pragma unroll
        for (int fn = 0; fn < 4; ++fn) {
            const int col = bn + wn * 64 + fn * 16 + lr16;
#pragma unroll
            for (int r = 0; r < 4; ++r) {
                float o = acc[fm][fn][r];
                if (EPI == 1) {
                    if (col < DM) o = phi_f(o) * 0.125f;
                    else if (col < 2 * DM) o = phi_f(o);
                }
                if (EPI == 2) {
                    ((float*)Cv)[(size_t)(row0 + r) * N + col] =
                        o + addx[(size_t)(row0 + r) * N + col];
                } else {
                    ((f16*)Cv)[(size_t)(row0 + r) * N + col] = (f16)o;
                }
            }
        }
    }
}

// ---------------- 3. conv boundary fixup: rows 0..2 of non-seq-start bands ------
__global__ __launch_bounds__(256) void fixconv_k(const f16* __restrict__ tailb,
                                                 f16* __restrict__ val,
                                                 const float* __restrict__ cw,
                                                 const float* __restrict__ cb)
{
    const int b = blockIdx.x;
    if ((b & 15) == 0) return;                    // sequence-start band: already exact
    const int c0 = threadIdx.x * 8;
    float um[3][8], u[3][8], g[3][8];
#pragma unroll
    for (int i = 0; i < 3; ++i) {
        const f16x8 a  = *(const f16x8*)(tailb + ((size_t)(b - 1) * 9 + 3 + i) * 2048 + c0);
        const f16x8 bb = *(const f16x8*)(tailb + ((size_t)b * 9 + i) * 2048 + c0);
        const f16x8 gg = *(const f16x8*)(tailb + ((size_t)b * 9 + 6 + i) * 2048 + c0);
#pragma unroll
        for (int j = 0; j < 8; ++j) {
            um[i][j] = (float)a[j]; u[i][j] = (float)bb[j]; g[i][j] = (float)gg[j];
        }
    }
#pragma unroll
    for (int r = 0; r < 3; ++r) {
        f16x8 o;
#pragma unroll
        for (int j = 0; j < 8; ++j) {
            const int cg = c0 + j;
            const float4 tp = *(const float4*)(cw + (size_t)cg * 4);
            float a = cb[cg];
            const float wnd[6] = {um[0][j], um[1][j], um[2][j], u[0][j], u[1][j], u[2][j]};
            a = fmaf(wnd[r],     tp.x, a);
            a = fmaf(wnd[r + 1], tp.y, a);
            a = fmaf(wnd[r + 2], tp.z, a);
            a = fmaf(wnd[r + 3], tp.w, a);
            o[j] = (f16)(silu_f(g[r][j]) * silu_f(a));
        }
        *(f16x8*)(val + ((size_t)b * 256 + r) * 2048 + c0) = o;
    }
}

// ---------------- 4a. per-chunk outer products: GT[b][h][ch][e][d] = (K^T V)^T --
__global__ __launch_bounds__(256) void gscan_g_k(const f16* __restrict__ qkv,
                                                 f16* __restrict__ GT)
{
    __shared__ float Ks[4096];
    __shared__ float Vs[4096];
    const int t = threadIdx.x, ch = blockIdx.x, h = blockIdx.y, b = blockIdx.z;
    const int r = t >> 2, c16 = (t & 3) * 16;
    const f16* kp = qkv + ((size_t)b * SEQL + ch * 64 + r) * 3072 + DM + h * 64 + c16;
#pragma unroll
    for (int i = 0; i < 2; ++i) {
        const f16x8 kv = *(const f16x8*)(kp + 8 * i);
        const f16x8 vv = *(const f16x8*)(kp + DM + 8 * i);
#pragma unroll
        for (int j = 0; j < 8; ++j) {
            Ks[r * 64 + c16 + 8 * i + j] = (float)kv[j];
            Vs[r * 64 + c16 + 8 * i + j] = (float)vv[j];
        }
    }
    __syncthreads();
    const int e4 = (t >> 4) * 4, d4 = (t & 15) * 4;
    float4 ag[4] = {};
#pragma unroll 4
    for (int c = 0; c < 64; ++c) {
        float va[4];
        *(float4*)va = *(const float4*)(Vs + c * 64 + e4);
        const float4 ka = *(const float4*)(Ks + c * 64 + d4);
        ag[0].x = fmaf(va[0], ka.x, ag[0].x); ag[0].y = fmaf(va[0], ka.y, ag[0].y);
        ag[0].z = fmaf(va[0], ka.z, ag[0].z); ag[0].w = fmaf(va[0], ka.w, ag[0].w);
        ag[1].x = fmaf(va[1], ka.x, ag[1].x); ag[1].y = fmaf(va[1], ka.y, ag[1].y);
        ag[1].z = fmaf(va[1], ka.z, ag[1].z); ag[1].w = fmaf(va[1], ka.w, ag[1].w);
        ag[2].x = fmaf(va[2], ka.x, ag[2].x); ag[2].y = fmaf(va[2], ka.y, ag[2].y);
        ag[2].z = fmaf(va[2], ka.z, ag[2].z); ag[2].w = fmaf(va[2], ka.w, ag[2].w);
        ag[3].x = fmaf(va[3], ka.x, ag[3].x); ag[3].y = fmaf(va[3], ka.y, ag[3].y);
        ag[3].z = fmaf(va[3], ka.z, ag[3].z); ag[3].w = fmaf(va[3], ka.w, ag[3].w);
    }
    f16* go = GT + (((size_t)b * 16 + h) * 64 + ch) * 4096 + e4 * 64 + d4;
#pragma unroll
    for (int i = 0; i < 4; ++i) {
        f16x4 o;
        o[0] = (f16)ag[i].x; o[1] = (f16)ag[i].y;
        o[2] = (f16)ag[i].z; o[3] = (f16)ag[i].w;
        *(f16x4*)(go + i * 64) = o;
    }
}

// ---------------- 4b. in-place exclusive prefix over chunks (f16x2, fp32 carry) -
__global__ __launch_bounds__(256) void gprefix_k(f16* __restrict__ G)
{
    const int bh = blockIdx.x >> 3, sl = blockIdx.x & 7;
    f16x2* p = (f16x2*)(G + (size_t)bh * 64 * 4096) + sl * 256 + threadIdx.x;
    float r0 = 0.0f, r1 = 0.0f;
#pragma unroll 4
    for (int ch = 0; ch < 64; ++ch) {
        const f16x2 g = *p;
        f16x2 o; o[0] = (f16)r0; o[1] = (f16)r1;
        *p = o;
        r0 += (float)g[0]; r1 += (float)g[1];
        p += 2048;
    }
}

// ---------------- 4c. per-chunk read via MFMA: y = q*M_excl + tril(q k^T) v -----
__global__ __launch_bounds__(256) void gscan_y_k(const f16* __restrict__ qkv,
                                                 const f16* __restrict__ GT,
                                                 f16* __restrict__ y)
{
    __shared__ __align__(16) char lds[40960];
    f16* Qs = (f16*)lds;
    f16* Ks = (f16*)(lds + 8192);
    f16* Ms = (f16*)(lds + 16384);
    f16* Vt = (f16*)(lds + 24576);
    f16* Ss = (f16*)(lds + 32768);

    const int t = threadIdx.x, ch = blockIdx.x, h = blockIdx.y, b = blockIdx.z;
    const int lane = t & 63, w = t >> 6;
    const int kb = lane >> 4, lr16 = lane & 15;

    const int r = t >> 2;
    const int c0 = (t & 3) * 2;
    const int rkey = (r >> 1) & 3;
    const f16* qp = qkv + ((size_t)b * SEQL + ch * 64 + r) * 3072 + h * 64;
    const f16* mp = GT + (((size_t)b * 16 + h) * 64 + ch) * 4096 + r * 64;
#pragma unroll
    for (int cc = 0; cc < 2; ++cc) {
        const int c = c0 + cc;
        const int sw = c ^ rkey;
        const f16x8 qv = *(const f16x8*)(qp + c * 8);
        const f16x8 kv = *(const f16x8*)(qp + DM + c * 8);
        const f16x8 vv = *(const f16x8*)(qp + 2 * DM + c * 8);
        const f16x8 mv = *(const f16x8*)(mp + c * 8);
        *(f16x8*)(Qs + r * 64 + sw * 8) = qv;
        *(f16x8*)(Ks + r * 64 + sw * 8) = kv;
        *(f16x8*)(Ms + r * 64 + sw * 8) = mv;
#pragma unroll
        for (int jj = 0; jj < 8; ++jj) {
            const int j = c * 8 + jj;
            Vt[j * 64 + ((((r >> 3) ^ ((j >> 1) & 3)) << 3) + (r & 7))] = vv[jj];
        }
    }
    __syncthreads();

    f16x8 af[2];
    {
        const int row = w * 16 + lr16;
        const int sz = (row >> 1) & 3;
        af[0] = *(const f16x8*)(Qs + row * 64 + (kb ^ sz) * 8);
        af[1] = *(const f16x8*)(Qs + row * 64 + (4 + (kb ^ sz)) * 8);
    }
    f32x4 accs[4];
#pragma unroll
    for (int te = 0; te < 4; ++te) accs[te] = (f32x4)0.0f;
#pragma unroll
    for (int te = 0; te < 4; ++te) {
        const int er = te * 16 + lr16;
        const int es = (er >> 1) & 3;
        const f16x8 b0 = *(const f16x8*)(Ks + er * 64 + (kb ^ es) * 8);
        const f16x8 b1 = *(const f16x8*)(Ks + er * 64 + (4 + (kb ^ es)) * 8);
        accs[te] = __builtin_amdgcn_mfma_f32_16x16x32_f16(af[0], b0, accs[te], 0, 0, 0);
        accs[te] = __builtin_amdgcn_mfma_f32_16x16x32_f16(af[1], b1, accs[te], 0, 0, 0);
    }
#pragma unroll
    for (int te = 0; te < 4; ++te)
#pragma unroll
        for (int rr = 0; rr < 4; ++rr) {
            const int rc = w * 16 + kb * 4 + rr;
            const int ce = te * 16 + lr16;
            const float v = (ce <= rc) ? accs[te][rr] : 0.0f;
            Ss[rc * 64 + ((((ce >> 3) ^ ((rc >> 1) & 3)) << 3) + (ce & 7))] = (f16)v;
        }
    __syncthreads();

    f16x8 as2[2];
    {
        const int row = w * 16 + lr16;
        const int sz = (row >> 1) & 3;
        as2[0] = *(const f16x8*)(Ss + row * 64 + (kb ^ sz) * 8);
        as2[1] = *(const f16x8*)(Ss + row * 64 + (4 + (kb ^ sz)) * 8);
    }
    f32x4 accy[4];
#pragma unroll
    for (int tj = 0; tj < 4; ++tj) accy[tj] = (f32x4)0.0f;
#pragma unroll
    for (int tj = 0; tj < 4; ++tj) {
        const int jr = tj * 16 + lr16;
        const int js = (jr >> 1) & 3;
        const f16x8 m0 = *(const f16x8*)(Ms + jr * 64 + (kb ^ js) * 8);
        const f16x8 m1 = *(const f16x8*)(Ms + jr * 64 + (4 + (kb ^ js)) * 8);
        const f16x8 v0 = *(const f16x8*)(Vt + jr * 64 + (kb ^ js) * 8);
        const f16x8 v1 = *(const f16x8*)(Vt + jr * 64 + (4 + (kb ^ js)) * 8);
        accy[tj] = __builtin_amdgcn_mfma_f32_16x16x32_f16(af[0],  m0, accy[tj], 0, 0, 0);
        accy[tj] = __builtin_amdgcn_mfma_f32_16x16x32_f16(af[1],  m1, accy[tj], 0, 0, 0);
        accy[tj] = __builtin_amdgcn_mfma_f32_16x16x32_f16(as2[0], v0, accy[tj], 0, 0, 0);
        accy[tj] = __builtin_amdgcn_mfma_f32_16x16x32_f16(as2[1], v1, accy[tj], 0, 0, 0);
    }
    f16* yo = y + ((size_t)b * SEQL + ch * 64) * DM + h * 64;
#pragma unroll
    for (int tj = 0; tj < 4; ++tj)
#pragma unroll
        for (int rr = 0; rr < 4; ++rr) {
            const int rc = w * 16 + kb * 4 + rr;
            yo[(size_t)rc * DM + tj * 16 + lr16] = (f16)accy[tj][rr];
        }
}

// ---------------- launch --------------------------------------------------------
extern "C" void kernel_launch(void* const* d_in, const int* in_sizes, int n_in,
                              void* d_out, int out_size, void* d_ws, size_t ws_size,
                              hipStream_t stream)
{
    const float* x      = (const float*)d_in[0];
    const float* norm_w = (const float*)d_in[1];
    const float* w_up   = (const float*)d_in[2];
    const float* w_gate = (const float*)d_in[3];
    const float* w_down = (const float*)d_in[4];
    const float* conv_w = (const float*)d_in[5];
    const float* conv_b = (const float*)d_in[6];
    const float* wq     = (const float*)d_in[7];
    const float* wk     = (const float*)d_in[8];
    const float* wv     = (const float*)d_in[9];
    const float* wo     = (const float*)d_in[10];
    float* out = (float*)d_out;

    const size_t BIG_NEED = 247463936ull;
    const bool big = ws_size >= BIG_NEED;

    if (big) {
        // layout (246.3 MB): val 64 | qkv 96 | hb 32 | fmtD 4 | fmtQKV 6 | fmtO 2 |
        //                    tail 2.25 | xn 32 | fmtUG 8 ; G (33.5) overlays xn+fmtUG
        char* p = (char*)d_ws;
        f16* val = (f16*)p;               p += (size_t)NRALL * 2048 * 2;
        f16* qkvb = (f16*)p;              p += (size_t)NRALL * 3072 * 2;
        f16* hb  = (f16*)p;               p += (size_t)NRALL * DM * 2;
        char* fmtD   = p;                 p += (size_t)64 * 1024 * 64;
        char* fmtQKV = p;                 p += (size_t)32 * 3072 * 64;
        char* fmtO   = p;                 p += (size_t)32 * 1024 * 64;
        f16* tailb = (f16*)p;             p += (size_t)64 * 9 * 2048 * 2;
        f16* xn = (f16*)p;                p += (size_t)NRALL * DM * 2;
        char* fmtUG  = p;
        f16* G = (f16*)xn;
        f16* yb = hb;

        prep_k<<<NRALL + 640, 256, 0, stream>>>(x, norm_w, xn, w_up, w_gate, w_down,
                                                wq, wk, wv, wo, fmtUG, fmtD, fmtQKV, fmtO);

        mg256_k<3><<<16 * 64, 1024, 0, stream>>>(xn, DM, fmtUG, val, 4096, DM, 16, nullptr,
                                                 conv_w, conv_b, tailb);
        fixconv_k<<<64, 256, 0, stream>>>(tailb, val, conv_w, conv_b);
        mg256_k<0><<<4 * 64, 1024, 0, stream>>>(val, 2048, fmtD, hb, 1024, DI, 4, nullptr);
        mg256_k<1><<<12 * 64, 1024, 0, stream>>>(hb, DM, fmtQKV, qkvb, 3072, DM, 12, nullptr);

        gscan_g_k<<<dim3(64, 16, 4), 256, 0, stream>>>(qkvb, G);
        gprefix_k<<<512, 256, 0, stream>>>(G);
        gscan_y_k<<<dim3(64, 16, 4), 256, 0, stream>>>(qkvb, G, yb);

        mg256_k<2><<<4 * 64, 1024, 0, stream>>>(yb, DM, fmtO, out, 1024, DM, 4, x);
    } else {
        // compact per-batch path (~109 MB)
        char* p = (char*)d_ws;
        f16* xn = (f16*)p;                p += (size_t)NRALL * DM * 2;
        f16* val = (f16*)p;               p += (size_t)SEQL * 2048 * 2;
        f16* qkvb = (f16*)p;              p += (size_t)SEQL * 3072 * 2;
        f16* hb  = (f16*)p;               p += (size_t)SEQL * DM * 2;
        f16* G = (f16*)p;                 p += (size_t)16 * 64 * 4096 * 2;
        char* fmtUG  = p;                 p += (size_t)32 * 4096 * 64;
        char* fmtD   = p;                 p += (size_t)64 * 1024 * 64;
        char* fmtQKV = p;                 p += (size_t)32 * 3072 * 64;
        char* fmtO   = p;                 p += (size_t)32 * 1024 * 64;
        f16* tailb = (f16*)p;
        f16* yb = hb;

        prep_k<<<NRALL + 640, 256, 0, stream>>>(x, norm_w, xn, w_up, w_gate, w_down,
                                                wq, wk, wv, wo, fmtUG, fmtD, fmtQKV, fmtO);

        for (int b = 0; b < 4; ++b) {
            const f16* xnb = xn + (size_t)b * SEQL * DM;
            mg256_k<3><<<16 * 16, 1024, 0, stream>>>(xnb, DM, fmtUG, val, 4096, DM, 16, nullptr,
                                                     conv_w, conv_b, tailb);
            fixconv_k<<<16, 256, 0, stream>>>(tailb, val, conv_w, conv_b);
            mg256_k<0><<<4 * 16, 1024, 0, stream>>>(val, 2048, fmtD, hb, 1024, DI, 4, nullptr);
            mg256_k<1><<<12 * 16, 1024, 0, stream>>>(hb, DM, fmtQKV, qkvb, 3072, DM, 12, nullptr);
            gscan_g_k<<<dim3(64, 16, 1), 256, 0, stream>>>(qkvb, G);
            gprefix_k<<<128, 256, 0, stream>>>(G);
            gscan_y_k<<<dim3(64, 16, 1), 256, 0, stream>>>(qkvb, G, yb);
            mg256_k<2><<<4 * 16, 1024, 0, stream>>>(yb, DM, fmtO,
                                                    out + (size_t)b * SEQL * DM, 1024, DM, 4,
                                                    x + (size_t)b * SEQL * DM);
        }
    }
}

// Round 19
// 501.814 us; speedup vs baseline: 7.0196x; 1.0297x over previous
//
#include <hip/hip_runtime.h>
#include <hip/hip_fp16.h>
#include <cstdint>

// Problem constants (B=4, S=4096, D=1024)
#define NRALL 16384
#define DM    1024
#define DI    2048
#define SEQL  4096

typedef _Float16 f16;
typedef _Float16 f16x8 __attribute__((ext_vector_type(8)));
typedef _Float16 f16x4 __attribute__((ext_vector_type(4)));
typedef _Float16 f16x2 __attribute__((ext_vector_type(2)));
typedef float    f32x4 __attribute__((ext_vector_type(4)));

__device__ __forceinline__ float phi_f(float t)  { return t > 0.0f ? t + 1.0f : __expf(t); }
__device__ __forceinline__ float silu_f(float t) { return t / (1.0f + __expf(-t)); }

#define GLDS16(g, l)                                                            \
    __builtin_amdgcn_global_load_lds(                                           \
        (const __attribute__((address_space(1))) void*)(g),                     \
        (__attribute__((address_space(3))) void*)(l), 16, 0, 0)

// epilogue tile index: XOR column with row-derived key -> kb groups hit disjoint
// bank sets. Key is a multiple of 8 -> even col pairs stay adjacent (f16x2-safe).
#define CSWZ(row, c) ((row) * 128 + ((c) ^ ((((row) >> 2) & 7) << 3)))

// ---------------- 1. merged prep: rmsnorm rows + weight format ------------------
// ng = n*mul + off : UG uses mul=2 (up even cols, gate odd) so the GEMM tile has
// up[c] and gate[c] together for the fused conv epilogue.
__device__ __forceinline__ void wfmt_one(const float* __restrict__ W, char* __restrict__ fmt,
                                         int n, int kt, int Nw, int Ntot, int mul, int off)
{
    const int ng = n * mul + off;
#pragma unroll
    for (int kh = 0; kh < 2; ++kh) {
        char* o = fmt + ((size_t)(kt * 2 + kh) * Ntot + ng) * 64;
#pragma unroll
        for (int c2 = 0; c2 < 4; ++c2) {
            f16x8 p;
#pragma unroll
            for (int j = 0; j < 8; ++j)
                p[j] = (f16)W[(size_t)(kt * 64 + kh * 32 + c2 * 8 + j) * Nw + n];
            *(f16x8*)(o + ((c2 ^ ((ng >> 1) & 3)) << 4)) = p;
        }
    }
}

__global__ __launch_bounds__(256) void prep_k(const float* __restrict__ x,
                                              const float* __restrict__ nw,
                                              f16* __restrict__ xn,
                                              const float* __restrict__ w_up,
                                              const float* __restrict__ w_gate,
                                              const float* __restrict__ w_down,
                                              const float* __restrict__ wq,
                                              const float* __restrict__ wk,
                                              const float* __restrict__ wv,
                                              const float* __restrict__ wo,
                                              char* __restrict__ fmtUG,
                                              char* __restrict__ fmtD,
                                              char* __restrict__ fmtQKV,
                                              char* __restrict__ fmtO)
{
    const int t = threadIdx.x;
    if (blockIdx.x < NRALL) {
        const int r = blockIdx.x;
        const float4 v = *(const float4*)(x + (size_t)r * DM + t * 4);
        float s = v.x * v.x + v.y * v.y + v.z * v.z + v.w * v.w;
#pragma unroll
        for (int m = 1; m < 64; m <<= 1) s += __shfl_xor(s, m);
        __shared__ float ws4[4];
        if ((t & 63) == 0) ws4[t >> 6] = s;
        __syncthreads();
        const float tot = ws4[0] + ws4[1] + ws4[2] + ws4[3];
        const float sc = rsqrtf(tot * (1.0f / DM) + 1e-5f);
        const float4 w = *(const float4*)(nw + t * 4);
        f16x4 o;
        o[0] = (f16)(v.x * sc * w.x); o[1] = (f16)(v.y * sc * w.y);
        o[2] = (f16)(v.z * sc * w.z); o[3] = (f16)(v.w * sc * w.w);
        *(f16x4*)(xn + (size_t)r * DM + t * 4) = o;
        return;
    }
    int id = blockIdx.x - NRALL;
    if (id < 128) { wfmt_one(w_up,   fmtUG,  (id % 8) * 256 + t, id / 8, DI, 4096, 2, 0); return; }
    id -= 128;
    if (id < 128) { wfmt_one(w_gate, fmtUG,  (id % 8) * 256 + t, id / 8, DI, 4096, 2, 1); return; }
    id -= 128;
    if (id < 128) { wfmt_one(w_down, fmtD,   (id % 4) * 256 + t, id / 4, DM, 1024, 1, 0); return; }
    id -= 128;
    if (id < 64)  { wfmt_one(wq,     fmtQKV, (id % 4) * 256 + t, id / 4, DM, 3072, 1, 0);    return; }
    id -= 64;
    if (id < 64)  { wfmt_one(wk,     fmtQKV, (id % 4) * 256 + t, id / 4, DM, 3072, 1, 1024); return; }
    id -= 64;
    if (id < 64)  { wfmt_one(wv,     fmtQKV, (id % 4) * 256 + t, id / 4, DM, 3072, 1, 2048); return; }
    id -= 64;
    wfmt_one(wo, fmtO, (id % 4) * 256 + t, id / 4, DM, 1024, 1, 0);
}

// ---------------- 2. 256x256 MFMA GEMM, 16 waves (4m x 4n), 8-phase -------------
// EPI: 0 f16 out; 1 qkv epilogue (phi ranges); 2 +addx fp32 out;
//      3 fused conv+silu+gate (UG interleaved tile -> val[.][2048]) + boundary dumps.
#define PH(p, ks, mh, STAGE_STMT)                                                 \
    {                                                                             \
        if ((mh) == 0) {                                                          \
            _Pragma("unroll")                                                     \
            for (int q = 0; q < 2; ++q) {                                         \
                const int row = wm * 64 + q * 16 + lr16;                          \
                af[q] = *(const f16x8*)(ldsb + (p) * 32768 + (ks) * 16384         \
                        + row * 64 + ((kb ^ ((row >> 1) & 3)) << 4));             \
            }                                                                     \
            _Pragma("unroll")                                                     \
            for (int q = 0; q < 4; ++q) {                                         \
                const int n = wn * 64 + q * 16 + lr16;                            \
                bf[q] = *(const f16x8*)(ldsb + 65536 + (p) * 32768 + (ks) * 16384 \
                        + n * 64 + ((kb ^ ((n >> 1) & 3)) << 4));                 \
            }                                                                     \
        } else {                                                                  \
            _Pragma("unroll")                                                     \
            for (int q = 0; q < 2; ++q) {                                         \
                const int row = wm * 64 + (q + 2) * 16 + lr16;                    \
                af[2 + q] = *(const f16x8*)(ldsb + (p) * 32768 + (ks) * 16384     \
                            + row * 64 + ((kb ^ ((row >> 1) & 3)) << 4));         \
            }                                                                     \
        }                                                                         \
        STAGE_STMT;                                                               \
        asm volatile("s_waitcnt vmcnt(3)" ::: "memory");                          \
        __builtin_amdgcn_sched_barrier(0);                                        \
        __builtin_amdgcn_s_barrier();                                             \
        asm volatile("s_waitcnt lgkmcnt(0)" ::: "memory");                        \
        __builtin_amdgcn_sched_barrier(0);                                        \
        __builtin_amdgcn_s_setprio(1);                                            \
        _Pragma("unroll")                                                         \
        for (int q = 0; q < 2; ++q) {                                             \
            acc[(mh) * 2 + q][0] = __builtin_amdgcn_mfma_f32_16x16x32_f16(        \
                af[(mh) * 2 + q], bf[0], acc[(mh) * 2 + q][0], 0, 0, 0);          \
            acc[(mh) * 2 + q][1] = __builtin_amdgcn_mfma_f32_16x16x32_f16(        \
                af[(mh) * 2 + q], bf[1], acc[(mh) * 2 + q][1], 0, 0, 0);          \
            acc[(mh) * 2 + q][2] = __builtin_amdgcn_mfma_f32_16x16x32_f16(        \
                af[(mh) * 2 + q], bf[2], acc[(mh) * 2 + q][2], 0, 0, 0);          \
            acc[(mh) * 2 + q][3] = __builtin_amdgcn_mfma_f32_16x16x32_f16(        \
                af[(mh) * 2 + q], bf[3], acc[(mh) * 2 + q][3], 0, 0, 0);          \
        }                                                                         \
        __builtin_amdgcn_s_setprio(0);                                            \
        __builtin_amdgcn_sched_barrier(0);                                        \
    }

template <int EPI>
__global__ __launch_bounds__(1024) void mg256_k(const f16* __restrict__ A, int lda,
                                                const char* __restrict__ fmt,
                                                void* __restrict__ Cv,
                                                int N, int K, int gx,
                                                const float* __restrict__ addx,
                                                const float* __restrict__ cw = nullptr,
                                                const float* __restrict__ cb = nullptr,
                                                f16* __restrict__ tailb = nullptr)
{
    __shared__ __align__(16) char ldsb[131072];

    const int t = threadIdx.x;
    int wid = blockIdx.x;
    { const int cpx = gridDim.x >> 3; wid = (wid & 7) * cpx + (wid >> 3); }  // XCD swizzle
    const int bx = wid % gx, by = wid / gx;
    const int bm = by * 256, bn = bx * 256;
    const int lane = t & 63, wv = t >> 6;
    const int wm = wv >> 2, wn = wv & 3;
    const int kb = lane >> 4, lr16 = lane & 15;
    const int NT = K >> 6;

    f32x4 acc[4][4];
#pragma unroll
    for (int i = 0; i < 4; ++i)
#pragma unroll
        for (int j = 0; j < 4; ++j) acc[i][j] = (f32x4)0.0f;

    const int arow = t >> 2;
    const int ac2 = (t & 3) ^ ((arow >> 1) & 3);
    const f16* Abase = A + (size_t)(bm + arow) * lda + ac2 * 8;
    const char* Bbase = fmt + (size_t)bn * 64 + (size_t)t * 16;
    const size_t BKstep = (size_t)N * 64;
    char* ldsT = ldsb + t * 16;

    auto STAGE_A = [&](int p, int kh, int kt) {
        GLDS16(Abase + kt * 64 + kh * 32, ldsT + p * 32768 + kh * 16384);
    };
    auto STAGE_B = [&](int p, int kh, int kt) {
        GLDS16(Bbase + (size_t)(kt * 2 + kh) * BKstep, ldsT + 65536 + p * 32768 + kh * 16384);
    };

    f16x8 af[4], bf[4];

    const int T1 = NT > 1 ? 1 : 0;
    STAGE_B(0, 0, 0); STAGE_A(0, 0, 0);
    STAGE_B(0, 1, 0); STAGE_A(0, 1, 0);
    STAGE_B(1, 0, T1); STAGE_A(1, 0, T1);
    asm volatile("s_waitcnt vmcnt(4)" ::: "memory");
    __builtin_amdgcn_s_barrier();
    __builtin_amdgcn_sched_barrier(0);

    const int NI = NT >> 1;
    for (int i = 0; i < NI; ++i) {
        const int tA = 2 * i + 1 < NT ? 2 * i + 1 : NT - 1;
        const int tB = 2 * i + 2 < NT ? 2 * i + 2 : NT - 1;
        const int tC = 2 * i + 3 < NT ? 2 * i + 3 : NT - 1;
        PH(0, 0, 0, STAGE_B(1, 1, tA))
        PH(0, 0, 1, STAGE_A(1, 1, tA))
        PH(0, 1, 0, STAGE_B(0, 0, tB))
        PH(0, 1, 1, STAGE_A(0, 0, tB))
        PH(1, 0, 0, STAGE_B(0, 1, tB))
        PH(1, 0, 1, STAGE_A(0, 1, tB))
        PH(1, 1, 0, STAGE_B(1, 0, tC))
        PH(1, 1, 1, STAGE_A(1, 0, tC))
    }
    asm volatile("s_waitcnt vmcnt(0)" ::: "memory");

    if (EPI == 3) {
        // ---- fused conv epilogue: acc tile -> LDS (up/gate split, CSWZ layout)
        __syncthreads();                    // all loop-phase LDS reads retired
        f16* upT = (f16*)ldsb;              // [256][128] via CSWZ
        f16* gtT = (f16*)(ldsb + 65536);
#pragma unroll
        for (int fm = 0; fm < 4; ++fm) {
            const int row = wm * 64 + fm * 16 + kb * 4;
#pragma unroll
            for (int fn = 0; fn < 4; ++fn) {
                const int col = wn * 64 + fn * 16 + lr16;
                f16* dst = (col & 1) ? gtT : upT;
                const int c = col >> 1;
#pragma unroll
                for (int r = 0; r < 4; ++r)
                    dst[CSWZ(row + r, c)] = (f16)acc[fm][fn][r];
            }
        }
        __syncthreads();
        // thread -> col-pair pi (2 channels), 16-row group rg: all LDS accesses dword
        const int pi = t & 63, rg = t >> 6;
        const int c2 = pi * 2;
        const int cg = bx * 128 + c2;
        const float4 tpa = *(const float4*)(cw + (size_t)cg * 4);
        const float4 tpb = *(const float4*)(cw + (size_t)(cg + 1) * 4);
        const float2 bias = *(const float2*)(cb + cg);
        const int r0 = rg * 16;
        float wa0 = 0.f, wa1 = 0.f, wa2 = 0.f, wb0 = 0.f, wb1 = 0.f, wb2 = 0.f;
        if (r0 > 0) {
            const f16x2 x0 = *(const f16x2*)(upT + CSWZ(r0 - 3, c2));
            const f16x2 x1 = *(const f16x2*)(upT + CSWZ(r0 - 2, c2));
            const f16x2 x2 = *(const f16x2*)(upT + CSWZ(r0 - 1, c2));
            wa0 = (float)x0[0]; wb0 = (float)x0[1];
            wa1 = (float)x1[0]; wb1 = (float)x1[1];
            wa2 = (float)x2[0]; wb2 = (float)x2[1];
        }
        f16* vout = (f16*)Cv;
#pragma unroll 4
        for (int i = 0; i < 16; ++i) {
            const int r = r0 + i;
            const f16x2 u2 = *(const f16x2*)(upT + CSWZ(r, c2));
            const f16x2 g2 = *(const f16x2*)(gtT + CSWZ(r, c2));
            const float ua = (float)u2[0], ub = (float)u2[1];
            float aa = bias.x, ab = bias.y;
            aa = fmaf(wa0, tpa.x, aa); aa = fmaf(wa1, tpa.y, aa);
            aa = fmaf(wa2, tpa.z, aa); aa = fmaf(ua,  tpa.w, aa);
            ab = fmaf(wb0, tpb.x, ab); ab = fmaf(wb1, tpb.y, ab);
            ab = fmaf(wb2, tpb.z, ab); ab = fmaf(ub,  tpb.w, ab);
            f16x2 o2;
            o2[0] = (f16)(silu_f((float)g2[0]) * silu_f(aa));
            o2[1] = (f16)(silu_f((float)g2[1]) * silu_f(ab));
            *(f16x2*)(vout + (size_t)(bm + r) * 2048 + cg) = o2;
            wa0 = wa1; wa1 = wa2; wa2 = ua;
            wb0 = wb1; wb1 = wb2; wb2 = ub;
        }
        const int band = bm >> 8;
        if (rg == 0) {                            // boundary dumps for fixup
#pragma unroll
            for (int i = 0; i < 3; ++i) {
                *(f16x2*)(tailb + ((size_t)band * 9 + i) * 2048 + cg) =
                    *(const f16x2*)(upT + CSWZ(i, c2));
                *(f16x2*)(tailb + ((size_t)band * 9 + 6 + i) * 2048 + cg) =
                    *(const f16x2*)(gtT + CSWZ(i, c2));
            }
        } else if (rg == 15) {
#pragma unroll
            for (int i = 0; i < 3; ++i)
                *(f16x2*)(tailb + ((size_t)band * 9 + 3 + i) * 2048 + cg) =
                    *(const f16x2*)(upT + CSWZ(253 + i, c2));
        }
        return;
    }

#pragma unroll
    for (int fm = 0; fm < 4; ++fm) {
        const int row0 = bm + wm * 64 + fm * 16 + kb * 4;
#pragma unroll
        for (int fn = 0; fn < 4; ++fn) {
            const int col = bn + wn * 64 + fn * 16 + lr16;
#pragma unroll
            for (int r = 0; r < 4; ++r) {
                float o = acc[fm][fn][r];
                if (EPI == 1) {
                    if (col < DM) o = phi_f(o) * 0.125f;
                    else if (col < 2 * DM) o = phi_f(o);
                }
                if (EPI == 2) {
                    ((float*)Cv)[(size_t)(row0 + r) * N + col] =
                        o + addx[(size_t)(row0 + r) * N + col];
                } else {
                    ((f16*)Cv)[(size_t)(row0 + r) * N + col] = (f16)o;
                }
            }
        }
    }
}

// ---------------- 3. conv boundary fixup: rows 0..2 of non-seq-start bands ------
__global__ __launch_bounds__(256) void fixconv_k(const f16* __restrict__ tailb,
                                                 f16* __restrict__ val,
                                                 const float* __restrict__ cw,
                                                 const float* __restrict__ cb)
{
    const int b = blockIdx.x;
    if ((b & 15) == 0) return;                    // sequence-start band: already exact
    const int c0 = threadIdx.x * 8;
    float um[3][8], u[3][8], g[3][8];
#pragma unroll
    for (int i = 0; i < 3; ++i) {
        const f16x8 a  = *(const f16x8*)(tailb + ((size_t)(b - 1) * 9 + 3 + i) * 2048 + c0);
        const f16x8 bb = *(const f16x8*)(tailb + ((size_t)b * 9 + i) * 2048 + c0);
        const f16x8 gg = *(const f16x8*)(tailb + ((size_t)b * 9 + 6 + i) * 2048 + c0);
#pragma unroll
        for (int j = 0; j < 8; ++j) {
            um[i][j] = (float)a[j]; u[i][j] = (float)bb[j]; g[i][j] = (float)gg[j];
        }
    }
#pragma unroll
    for (int r = 0; r < 3; ++r) {
        f16x8 o;
#pragma unroll
        for (int j = 0; j < 8; ++j) {
            const int cg = c0 + j;
            const float4 tp = *(const float4*)(cw + (size_t)cg * 4);
            float a = cb[cg];
            const float wnd[6] = {um[0][j], um[1][j], um[2][j], u[0][j], u[1][j], u[2][j]};
            a = fmaf(wnd[r],     tp.x, a);
            a = fmaf(wnd[r + 1], tp.y, a);
            a = fmaf(wnd[r + 2], tp.z, a);
            a = fmaf(wnd[r + 3], tp.w, a);
            o[j] = (f16)(silu_f(g[r][j]) * silu_f(a));
        }
        *(f16x8*)(val + ((size_t)b * 256 + r) * 2048 + c0) = o;
    }
}

// ---------------- 4a. per-chunk outer products via MFMA ------------------------
// GT[e][d] = sum_c V[c][e] * K[c][d]  ==  mfma(A=V^T, B=K^T).
// Both operands scalar-transposed into LDS with the gscan_y-proven swizzle:
// write T[j*64 + (((r>>3)^((j>>1)&3))<<3) + (r&7)], read chunk (kb^((row>>1)&3)).
__global__ __launch_bounds__(256) void gscan_g_k(const f16* __restrict__ qkv,
                                                 f16* __restrict__ GT)
{
    __shared__ __align__(16) char lds[16384];
    f16* Kt = (f16*)lds;             // Kt[d][c'] = K[c][d]
    f16* Vt = (f16*)(lds + 8192);    // Vt[e][c'] = V[c][e]

    const int t = threadIdx.x, ch = blockIdx.x, h = blockIdx.y, b = blockIdx.z;
    const int lane = t & 63, w = t >> 6;
    const int kb = lane >> 4, lr16 = lane & 15;

    const int r = t >> 2;            // source row c
    const int c0 = (t & 3) * 2;      // two 8-wide chunks along d/e
    const f16* kp = qkv + ((size_t)b * SEQL + ch * 64 + r) * 3072 + DM + h * 64;
#pragma unroll
    for (int cc = 0; cc < 2; ++cc) {
        const int c = c0 + cc;
        const f16x8 kv = *(const f16x8*)(kp + c * 8);
        const f16x8 vv = *(const f16x8*)(kp + DM + c * 8);
#pragma unroll
        for (int jj = 0; jj < 8; ++jj) {
            const int j = c * 8 + jj;
            const int pos = j * 64 + ((((r >> 3) ^ ((j >> 1) & 3)) << 3) + (r & 7));
            Kt[pos] = kv[jj];
            Vt[pos] = vv[jj];
        }
    }
    __syncthreads();

    // A-frags: e-row tile of this wave (rows w*16..+15), K=64 -> 2 frags
    f16x8 av[2];
    {
        const int row = w * 16 + lr16;
        const int js = (row >> 1) & 3;
        av[0] = *(const f16x8*)(Vt + row * 64 + (kb ^ js) * 8);
        av[1] = *(const f16x8*)(Vt + row * 64 + (4 + (kb ^ js)) * 8);
    }
    f32x4 accg[4];
#pragma unroll
    for (int tj = 0; tj < 4; ++tj) accg[tj] = (f32x4)0.0f;
#pragma unroll
    for (int tj = 0; tj < 4; ++tj) {
        const int dr = tj * 16 + lr16;
        const int ds_ = (dr >> 1) & 3;
        const f16x8 b0 = *(const f16x8*)(Kt + dr * 64 + (kb ^ ds_) * 8);
        const f16x8 b1 = *(const f16x8*)(Kt + dr * 64 + (4 + (kb ^ ds_)) * 8);
        accg[tj] = __builtin_amdgcn_mfma_f32_16x16x32_f16(av[0], b0, accg[tj], 0, 0, 0);
        accg[tj] = __builtin_amdgcn_mfma_f32_16x16x32_f16(av[1], b1, accg[tj], 0, 0, 0);
    }
    // C layout: col=lane&15 (d within tile), row=(lane>>4)*4+rr (e within tile)
    f16* go = GT + (((size_t)b * 16 + h) * 64 + ch) * 4096;
#pragma unroll
    for (int tj = 0; tj < 4; ++tj)
#pragma unroll
        for (int rr = 0; rr < 4; ++rr)
            go[(w * 16 + kb * 4 + rr) * 64 + tj * 16 + lr16] = (f16)accg[tj][rr];
}

// ---------------- 4b. in-place exclusive prefix over chunks (f16x2, fp32 carry) -
__global__ __launch_bounds__(256) void gprefix_k(f16* __restrict__ G)
{
    const int bh = blockIdx.x >> 3, sl = blockIdx.x & 7;
    f16x2* p = (f16x2*)(G + (size_t)bh * 64 * 4096) + sl * 256 + threadIdx.x;
    float r0 = 0.0f, r1 = 0.0f;
#pragma unroll 4
    for (int ch = 0; ch < 64; ++ch) {
        const f16x2 g = *p;
        f16x2 o; o[0] = (f16)r0; o[1] = (f16)r1;
        *p = o;
        r0 += (float)g[0]; r1 += (float)g[1];
        p += 2048;
    }
}

// ---------------- 4c. per-chunk read via MFMA: y = q*M_excl + tril(q k^T) v -----
__global__ __launch_bounds__(256) void gscan_y_k(const f16* __restrict__ qkv,
                                                 const f16* __restrict__ GT,
                                                 f16* __restrict__ y)
{
    __shared__ __align__(16) char lds[40960];
    f16* Qs = (f16*)lds;
    f16* Ks = (f16*)(lds + 8192);
    f16* Ms = (f16*)(lds + 16384);
    f16* Vt = (f16*)(lds + 24576);
    f16* Ss = (f16*)(lds + 32768);

    const int t = threadIdx.x, ch = blockIdx.x, h = blockIdx.y, b = blockIdx.z;
    const int lane = t & 63, w = t >> 6;
    const int kb = lane >> 4, lr16 = lane & 15;

    const int r = t >> 2;
    const int c0 = (t & 3) * 2;
    const int rkey = (r >> 1) & 3;
    const f16* qp = qkv + ((size_t)b * SEQL + ch * 64 + r) * 3072 + h * 64;
    const f16* mp = GT + (((size_t)b * 16 + h) * 64 + ch) * 4096 + r * 64;
#pragma unroll
    for (int cc = 0; cc < 2; ++cc) {
        const int c = c0 + cc;
        const int sw = c ^ rkey;
        const f16x8 qv = *(const f16x8*)(qp + c * 8);
        const f16x8 kv = *(const f16x8*)(qp + DM + c * 8);
        const f16x8 vv = *(const f16x8*)(qp + 2 * DM + c * 8);
        const f16x8 mv = *(const f16x8*)(mp + c * 8);
        *(f16x8*)(Qs + r * 64 + sw * 8) = qv;
        *(f16x8*)(Ks + r * 64 + sw * 8) = kv;
        *(f16x8*)(Ms + r * 64 + sw * 8) = mv;
#pragma unroll
        for (int jj = 0; jj < 8; ++jj) {
            const int j = c * 8 + jj;
            Vt[j * 64 + ((((r >> 3) ^ ((j >> 1) & 3)) << 3) + (r & 7))] = vv[jj];
        }
    }
    __syncthreads();

    f16x8 af[2];
    {
        const int row = w * 16 + lr16;
        const int sz = (row >> 1) & 3;
        af[0] = *(const f16x8*)(Qs + row * 64 + (kb ^ sz) * 8);
        af[1] = *(const f16x8*)(Qs + row * 64 + (4 + (kb ^ sz)) * 8);
    }
    f32x4 accs[4];
#pragma unroll
    for (int te = 0; te < 4; ++te) accs[te] = (f32x4)0.0f;
#pragma unroll
    for (int te = 0; te < 4; ++te) {
        const int er = te * 16 + lr16;
        const int es = (er >> 1) & 3;
        const f16x8 b0 = *(const f16x8*)(Ks + er * 64 + (kb ^ es) * 8);
        const f16x8 b1 = *(const f16x8*)(Ks + er * 64 + (4 + (kb ^ es)) * 8);
        accs[te] = __builtin_amdgcn_mfma_f32_16x16x32_f16(af[0], b0, accs[te], 0, 0, 0);
        accs[te] = __builtin_amdgcn_mfma_f32_16x16x32_f16(af[1], b1, accs[te], 0, 0, 0);
    }
#pragma unroll
    for (int te = 0; te < 4; ++te)
#pragma unroll
        for (int rr = 0; rr < 4; ++rr) {
            const int rc = w * 16 + kb * 4 + rr;
            const int ce = te * 16 + lr16;
            const float v = (ce <= rc) ? accs[te][rr] : 0.0f;
            Ss[rc * 64 + ((((ce >> 3) ^ ((rc >> 1) & 3)) << 3) + (ce & 7))] = (f16)v;
        }
    __syncthreads();

    f16x8 as2[2];
    {
        const int row = w * 16 + lr16;
        const int sz = (row >> 1) & 3;
        as2[0] = *(const f16x8*)(Ss + row * 64 + (kb ^ sz) * 8);
        as2[1] = *(const f16x8*)(Ss + row * 64 + (4 + (kb ^ sz)) * 8);
    }
    f32x4 accy[4];
#pragma unroll
    for (int tj = 0; tj < 4; ++tj) accy[tj] = (f32x4)0.0f;
#pragma unroll
    for (int tj = 0; tj < 4; ++tj) {
        const int jr = tj * 16 + lr16;
        const int js = (jr >> 1) & 3;
        const f16x8 m0 = *(const f16x8*)(Ms + jr * 64 + (kb ^ js) * 8);
        const f16x8 m1 = *(const f16x8*)(Ms + jr * 64 + (4 + (kb ^ js)) * 8);
        const f16x8 v0 = *(const f16x8*)(Vt + jr * 64 + (kb ^ js) * 8);
        const f16x8 v1 = *(const f16x8*)(Vt + jr * 64 + (4 + (kb ^ js)) * 8);
        accy[tj] = __builtin_amdgcn_mfma_f32_16x16x32_f16(af[0],  m0, accy[tj], 0, 0, 0);
        accy[tj] = __builtin_amdgcn_mfma_f32_16x16x32_f16(af[1],  m1, accy[tj], 0, 0, 0);
        accy[tj] = __builtin_amdgcn_mfma_f32_16x16x32_f16(as2[0], v0, accy[tj], 0, 0, 0);
        accy[tj] = __builtin_amdgcn_mfma_f32_16x16x32_f16(as2[1], v1, accy[tj], 0, 0, 0);
    }
    f16* yo = y + ((size_t)b * SEQL + ch * 64) * DM + h * 64;
#pragma unroll
    for (int tj = 0; tj < 4; ++tj)
#pragma unroll
        for (int rr = 0; rr < 4; ++rr) {
            const int rc = w * 16 + kb * 4 + rr;
            yo[(size_t)rc * DM + tj * 16 + lr16] = (f16)accy[tj][rr];
        }
}

// ---------------- launch --------------------------------------------------------
extern "C" void kernel_launch(void* const* d_in, const int* in_sizes, int n_in,
                              void* d_out, int out_size, void* d_ws, size_t ws_size,
                              hipStream_t stream)
{
    const float* x      = (const float*)d_in[0];
    const float* norm_w = (const float*)d_in[1];
    const float* w_up   = (const float*)d_in[2];
    const float* w_gate = (const float*)d_in[3];
    const float* w_down = (const float*)d_in[4];
    const float* conv_w = (const float*)d_in[5];
    const float* conv_b = (const float*)d_in[6];
    const float* wq     = (const float*)d_in[7];
    const float* wk     = (const float*)d_in[8];
    const float* wv     = (const float*)d_in[9];
    const float* wo     = (const float*)d_in[10];
    float* out = (float*)d_out;

    const size_t BIG_NEED = 247463936ull;
    const bool big = ws_size >= BIG_NEED;

    if (big) {
        // layout (246.3 MB): val 64 | qkv 96 | hb 32 | fmtD 4 | fmtQKV 6 | fmtO 2 |
        //                    tail 2.25 | xn 32 | fmtUG 8 ; G (33.5) overlays xn+fmtUG
        char* p = (char*)d_ws;
        f16* val = (f16*)p;               p += (size_t)NRALL * 2048 * 2;
        f16* qkvb = (f16*)p;              p += (size_t)NRALL * 3072 * 2;
        f16* hb  = (f16*)p;               p += (size_t)NRALL * DM * 2;
        char* fmtD   = p;                 p += (size_t)64 * 1024 * 64;
        char* fmtQKV = p;                 p += (size_t)32 * 3072 * 64;
        char* fmtO   = p;                 p += (size_t)32 * 1024 * 64;
        f16* tailb = (f16*)p;             p += (size_t)64 * 9 * 2048 * 2;
        f16* xn = (f16*)p;                p += (size_t)NRALL * DM * 2;
        char* fmtUG  = p;
        f16* G = (f16*)xn;
        f16* yb = hb;

        prep_k<<<NRALL + 640, 256, 0, stream>>>(x, norm_w, xn, w_up, w_gate, w_down,
                                                wq, wk, wv, wo, fmtUG, fmtD, fmtQKV, fmtO);

        mg256_k<3><<<16 * 64, 1024, 0, stream>>>(xn, DM, fmtUG, val, 4096, DM, 16, nullptr,
                                                 conv_w, conv_b, tailb);
        fixconv_k<<<64, 256, 0, stream>>>(tailb, val, conv_w, conv_b);
        mg256_k<0><<<4 * 64, 1024, 0, stream>>>(val, 2048, fmtD, hb, 1024, DI, 4, nullptr);
        mg256_k<1><<<12 * 64, 1024, 0, stream>>>(hb, DM, fmtQKV, qkvb, 3072, DM, 12, nullptr);

        gscan_g_k<<<dim3(64, 16, 4), 256, 0, stream>>>(qkvb, G);
        gprefix_k<<<512, 256, 0, stream>>>(G);
        gscan_y_k<<<dim3(64, 16, 4), 256, 0, stream>>>(qkvb, G, yb);

        mg256_k<2><<<4 * 64, 1024, 0, stream>>>(yb, DM, fmtO, out, 1024, DM, 4, x);
    } else {
        // compact per-batch path (~109 MB)
        char* p = (char*)d_ws;
        f16* xn = (f16*)p;                p += (size_t)NRALL * DM * 2;
        f16* val = (f16*)p;               p += (size_t)SEQL * 2048 * 2;
        f16* qkvb = (f16*)p;              p += (size_t)SEQL * 3072 * 2;
        f16* hb  = (f16*)p;               p += (size_t)SEQL * DM * 2;
        f16* G = (f16*)p;                 p += (size_t)16 * 64 * 4096 * 2;
        char* fmtUG  = p;                 p += (size_t)32 * 4096 * 64;
        char* fmtD   = p;                 p += (size_t)64 * 1024 * 64;
        char* fmtQKV = p;                 p += (size_t)32 * 3072 * 64;
        char* fmtO   = p;                 p += (size_t)32 * 1024 * 64;
        f16* tailb = (f16*)p;
        f16* yb = hb;

        prep_k<<<NRALL + 640, 256, 0, stream>>>(x, norm_w, xn, w_up, w_gate, w_down,
                                                wq, wk, wv, wo, fmtUG, fmtD, fmtQKV, fmtO);

        for (int b = 0; b < 4; ++b) {
            const f16* xnb = xn + (size_t)b * SEQL * DM;
            mg256_k<3><<<16 * 16, 1024, 0, stream>>>(xnb, DM, fmtUG, val, 4096, DM, 16, nullptr,
                                                     conv_w, conv_b, tailb);
            fixconv_k<<<16, 256, 0, stream>>>(tailb, val, conv_w, conv_b);
            mg256_k<0><<<4 * 16, 1024, 0, stream>>>(val, 2048, fmtD, hb, 1024, DI, 4, nullptr);
            mg256_k<1><<<12 * 16, 1024, 0, stream>>>(hb, DM, fmtQKV, qkvb, 3072, DM, 12, nullptr);
            gscan_g_k<<<dim3(64, 16, 1), 256, 0, stream>>>(qkvb, G);
            gprefix_k<<<128, 256, 0, stream>>>(G);
            gscan_y_k<<<dim3(64, 16, 1), 256, 0, stream>>>(qkvb, G, yb);
            mg256_k<2><<<4 * 16, 1024, 0, stream>>>(yb, DM, fmtO,
                                                    out + (size_t)b * SEQL * DM, 1024, DM, 4,
                                                    x + (size_t)b * SEQL * DM);
        }
    }
}